// Round 7
// baseline (362.871 us; speedup 1.0000x reference)
//
#include <hip/hip_runtime.h>
#include <hip/hip_cooperative_groups.h>
#include <math.h>

namespace cg = cooperative_groups;

#define B_  2
#define T_  2048
#define D_  1024
#define H_  16
#define HD_ 64
#define VTS (T_ + 64)   // padded vt row stride (halves)

typedef float    f32x4  __attribute__((ext_vector_type(4)));
typedef _Float16 half8  __attribute__((ext_vector_type(8)));
typedef _Float16 half4v __attribute__((ext_vector_type(4)));

#define GLOAD_LDS16(g, l)                                                     \
    __builtin_amdgcn_global_load_lds(                                         \
        (__attribute__((address_space(1))) void*)(g),                         \
        (__attribute__((address_space(3))) void*)(l), 16, 0, 0)

// ===========================================================================
// Single cooperative mega-kernel: 5 phases, 4 grid.sync() barriers.
// Rationale: 5-launch pipeline carried ~10-15us dispatch overhead per launch
// (kernel-sum model ~75-100us vs measured 169us; all kernels < 42us fills).
// Phase bodies are the R6-proven units verbatim; __shared__ lives in a 40KB
// union; phases grid-stride. All XCD mappings keyed on v%8 (GS % 8 == 0).
// ===========================================================================

// ---- phase 0 helper: 32x32 f32->f16 transpose through LDS ----
__device__ __forceinline__ void transpose_unit(
    unsigned char* smemraw, const float* __restrict__ in,
    _Float16* __restrict__ out, int R, int C, int r0, int c0, int tid)
{
    float (*tile)[33] = (float (*)[33])smemraw;   // 32*33*4 = 4224 B
    const int tx = tid & 31, ty = tid >> 5;
    #pragma unroll
    for (int q = 0; q < 4; ++q)
        tile[ty + 8 * q][tx] = in[(size_t)(r0 + ty + 8 * q) * C + c0 + tx];
    __syncthreads();
    #pragma unroll
    for (int q = 0; q < 4; ++q)
        out[(size_t)(c0 + ty + 8 * q) * R + r0 + tx] = (_Float16)tile[tx][ty + 8 * q];
    __syncthreads();   // protect LDS reuse by the next grid-stride unit
}

__device__ __forceinline__ void prep_unit(
    int bx, unsigned char* smem,
    const float* __restrict__ x, _Float16* __restrict__ x16,
    const float* __restrict__ w_qkv, _Float16* __restrict__ wqkvT,
    const float* __restrict__ w_out, _Float16* __restrict__ woutT)
{
    const int tid = threadIdx.x;
    if (bx < 4096) {
        const int i = (bx * 256 + tid) * 4;
        float4 v = *(const float4*)(x + i);
        half4v h;
        h[0] = (_Float16)v.x; h[1] = (_Float16)v.y;
        h[2] = (_Float16)v.z; h[3] = (_Float16)v.w;
        *(half4v*)(x16 + i) = h;
    } else if (bx < 7168) {
        const int bi = bx - 4096;                 // w_qkv: 1024 x 3072
        transpose_unit(smem, w_qkv, wqkvT, D_, 3 * D_,
                       (bi / 96) * 32, (bi % 96) * 32, tid);
    } else {
        const int bi = bx - 7168;                 // w_out: 1024 x 1024
        transpose_unit(smem, w_out, woutT, D_, D_,
                       (bi / 32) * 32, (bi % 32) * 32, tid);
    }
}

// ---- shared GEMM main loop (128x128 tile, BK=64, XOR-swizzled LDS) ----
#define GEMM_BODY_P(BX, BY)                                                   \
    const int tid  = threadIdx.x;                                             \
    const int lane = tid & 63;                                                \
    const int w    = tid >> 6;                                                \
    const int wm   = (w >> 1) * 64;                                           \
    const int wn   = (w & 1) * 64;                                            \
    const int srow = lane >> 3;               /* 0..7 */                      \
    const int sseg = (lane & 7) ^ srow;       /* swizzled fetch seg */        \
    const _Float16* gA = A  + (size_t)((BY) * 128 + w * 32 + srow) * K + sseg * 8; \
    const _Float16* gB = Bt + (size_t)((BX) * 128 + w * 32 + srow) * K + sseg * 8; \
    _Float16* lA = &As[(w * 32) * 64];                                        \
    _Float16* lB = &Bs[(w * 32) * 64];                                        \
    f32x4 acc[4][4];                                                          \
    _Pragma("unroll")                                                         \
    for (int i = 0; i < 4; ++i)                                               \
        _Pragma("unroll")                                                     \
        for (int j = 0; j < 4; ++j)                                           \
            _Pragma("unroll")                                                 \
            for (int rr = 0; rr < 4; ++rr) acc[i][j][rr] = 0.f;               \
    const int fr  = lane & 15;                                                \
    const int fq  = lane >> 4;                                                \
    const int fsw = fr & 7;                                                   \
    for (int k0 = 0; k0 < K; k0 += 64) {                                      \
        _Pragma("unroll")                                                     \
        for (int i = 0; i < 4; ++i) {                                         \
            GLOAD_LDS16(gA + (size_t)(i * 8) * K + k0, lA + i * 8 * 64);      \
            GLOAD_LDS16(gB + (size_t)(i * 8) * K + k0, lB + i * 8 * 64);      \
        }                                                                     \
        __syncthreads();                                                      \
        _Pragma("unroll")                                                     \
        for (int kk = 0; kk < 2; ++kk) {                                      \
            half8 af[4], bf[4];                                               \
            _Pragma("unroll")                                                 \
            for (int i = 0; i < 4; ++i)                                       \
                af[i] = *(const half8*)&As[(wm + i * 16 + fr) * 64 +          \
                                           ((kk * 4 + fq) ^ fsw) * 8];        \
            _Pragma("unroll")                                                 \
            for (int j = 0; j < 4; ++j)                                       \
                bf[j] = *(const half8*)&Bs[(wn + j * 16 + fr) * 64 +          \
                                           ((kk * 4 + fq) ^ fsw) * 8];        \
            _Pragma("unroll")                                                 \
            for (int i = 0; i < 4; ++i)                                       \
                _Pragma("unroll")                                             \
                for (int j = 0; j < 4; ++j)                                   \
                    acc[i][j] = __builtin_amdgcn_mfma_f32_16x16x32_f16(       \
                        af[i], bf[j], acc[i][j], 0, 0, 0);                    \
        }                                                                     \
        __syncthreads();                                                      \
    }

// ---- phase 1: qkv GEMM unit (head-major f16 out), [R2-proven mapping] ----
__device__ __forceinline__ void qkv_unit(
    int v, unsigned char* smem,
    const _Float16* __restrict__ A, const _Float16* __restrict__ Bt,
    const float* __restrict__ bias, _Float16* __restrict__ C, int M, int N, int K)
{
    _Float16* As = (_Float16*)smem;               // 16384 B
    _Float16* Bs = (_Float16*)(smem + 16384);     // 16384 B
    const int wgid = (v & 7) * 96 + (v >> 3);     // bijective (768 % 8 == 0)
    const int bx   = wgid % 24;                   // N tile
    const int by   = wgid / 24;                   // M tile
    GEMM_BODY_P(bx, by)
    #pragma unroll
    for (int j = 0; j < 4; ++j) {
        const int col = bx * 128 + wn + j * 16 + fr;
        const float bv = bias[col];
        const int which = col >> 10;
        const int hh    = (col >> 6) & 15;
        const int e     = col & 63;
        #pragma unroll
        for (int i = 0; i < 4; ++i) {
            const int row = by * 128 + wm + i * 16 + fq * 4;
            #pragma unroll
            for (int rr = 0; rr < 4; ++rr) {
                const int rowr = row + rr;
                const int b2 = rowr >> 11, t = rowr & 2047;
                const size_t dst =
                    (((size_t)(b2 * 16 + hh) * 3 + which) * 2048 + t) * 64 + e;
                C[dst] = (_Float16)(acc[i][j][rr] + bv);
            }
        }
    }
}

// ---- phase 4: out-projection GEMM unit (128x64 tile), [R2-proven] ----
__device__ __forceinline__ void out_unit(
    int v, unsigned char* smem,
    const _Float16* __restrict__ A, const _Float16* __restrict__ Bt,
    const float* __restrict__ bias, float* __restrict__ C, int M, int N, int K)
{
    _Float16* As = (_Float16*)smem;               // 16384 B
    _Float16* Bs = (_Float16*)(smem + 16384);     // 8192 B
    const int wgid = (v & 7) * 64 + (v >> 3);     // bijective (512 % 8 == 0)
    const int bx   = wgid & 15;                   // N tile (64 wide)
    const int by   = wgid >> 4;                   // M tile (128 tall)
    const int tid  = threadIdx.x;
    const int lane = tid & 63;
    const int w    = tid >> 6;
    const int srow = lane >> 3;
    const int sseg = (lane & 7) ^ srow;
    const _Float16* gA = A  + (size_t)(by * 128 + w * 32 + srow) * K + sseg * 8;
    const _Float16* gB = Bt + (size_t)(bx * 64  + w * 16 + srow) * K + sseg * 8;
    _Float16* lA = &As[(w * 32) * 64];
    _Float16* lB = &Bs[(w * 16) * 64];
    f32x4 acc[2][4];
    #pragma unroll
    for (int i = 0; i < 2; ++i)
        #pragma unroll
        for (int j = 0; j < 4; ++j)
            #pragma unroll
            for (int rr = 0; rr < 4; ++rr) acc[i][j][rr] = 0.f;
    const int fr  = lane & 15;
    const int fq  = lane >> 4;
    const int fsw = fr & 7;
    for (int k0 = 0; k0 < K; k0 += 64) {
        #pragma unroll
        for (int i = 0; i < 4; ++i)
            GLOAD_LDS16(gA + (size_t)(i * 8) * K + k0, lA + i * 8 * 64);
        #pragma unroll
        for (int i = 0; i < 2; ++i)
            GLOAD_LDS16(gB + (size_t)(i * 8) * K + k0, lB + i * 8 * 64);
        __syncthreads();
        #pragma unroll
        for (int kk = 0; kk < 2; ++kk) {
            half8 af[2], bf[4];
            #pragma unroll
            for (int i = 0; i < 2; ++i)
                af[i] = *(const half8*)&As[(w * 32 + i * 16 + fr) * 64 +
                                           ((kk * 4 + fq) ^ fsw) * 8];
            #pragma unroll
            for (int j = 0; j < 4; ++j)
                bf[j] = *(const half8*)&Bs[(j * 16 + fr) * 64 +
                                           ((kk * 4 + fq) ^ fsw) * 8];
            #pragma unroll
            for (int i = 0; i < 2; ++i)
                #pragma unroll
                for (int j = 0; j < 4; ++j)
                    acc[i][j] = __builtin_amdgcn_mfma_f32_16x16x32_f16(
                        af[i], bf[j], acc[i][j], 0, 0, 0);
        }
        __syncthreads();
    }
    #pragma unroll
    for (int j = 0; j < 4; ++j) {
        const int col = bx * 64 + j * 16 + fr;
        const float bv = bias[col];
        #pragma unroll
        for (int i = 0; i < 2; ++i) {
            const int row = by * 128 + w * 32 + i * 16 + fq * 4;
            #pragma unroll
            for (int rr = 0; rr < 4; ++rr)
                C[(size_t)(row + rr) * N + col] = acc[i][j][rr] + bv;
        }
    }
}

// ---- phase 2: V gather+transpose unit, [R2-proven mapping] ----
__device__ __forceinline__ void vt_unit(
    int v, unsigned char* smem,
    const _Float16* __restrict__ qkv, const int* __restrict__ periods,
    _Float16* __restrict__ vt)
{
    _Float16 (*tile)[72] = (_Float16 (*)[72])smem;   // 64*72*2 = 9216 B
    const int s   = v >> 3;                       // 0..127
    const int bh  = (v & 7) + 8 * (s >> 5);
    const int c0  = (s & 31) * 64;
    int p = periods[bh]; if (p < 1) p = 1;
    const int tid = threadIdx.x;
    const int rr = tid >> 2, seg = (tid & 3) * 16;

    const int c = c0 + rr;
    int r = 0, off = 0;
    for (; r < p - 1; ++r) {
        const int n = (T_ - 1 - r) / p + 1;
        if (c < off + n) break;
        off += n;
    }
    const int t = r + (c - off) * p;

    const size_t hs = (size_t)T_ * HD_;
    const _Float16* vrow = qkv + ((size_t)bh * 3 + 2) * hs + (size_t)t * HD_ + seg;
    *(half8*)&tile[rr][seg]     = *(const half8*)(vrow);
    *(half8*)&tile[rr][seg + 8] = *(const half8*)(vrow + 8);
    __syncthreads();

    _Float16* dst = vt + ((size_t)bh * HD_ + rr) * VTS + c0 + seg;
    half8 o0, o1;
    #pragma unroll
    for (int i = 0; i < 8; ++i) o0[i] = tile[seg + i][rr];
    #pragma unroll
    for (int i = 0; i < 8; ++i) o1[i] = tile[seg + 8 + i][rr];
    *(half8*)(dst)     = o0;
    *(half8*)(dst + 8) = o1;
    __syncthreads();   // protect LDS reuse by the next grid-stride unit
}

// ---- phase 3: periodic-sparse MFMA attention unit, [R6-proven body] ----
__device__ __forceinline__ void attn_unit(
    int v, unsigned char* smem,
    const _Float16* __restrict__ qkv, const _Float16* __restrict__ vt,
    const int* __restrict__ periods, _Float16* __restrict__ ao)
{
    _Float16* Kt0 = (_Float16*)(smem);            // 8192 B each
    _Float16* Kt1 = (_Float16*)(smem + 8192);
    _Float16* Vt0 = (_Float16*)(smem + 16384);
    _Float16* Vt1 = (_Float16*)(smem + 24576);
    _Float16 (*Ps)[16 * 64] = (_Float16 (*)[16 * 64])(smem + 32768); // 8192 B

    const int s   = v >> 3;                       // 0..191
    const int bh  = (v & 7) + 8 * (s / 48);       // bh == xcd (mod 8)
    int tix = s % 48;

    int p = periods[bh]; if (p < 1) p = 1;

    int r = -1, q0 = 0, n_r = 0, off = 0;
    for (int rr2 = 0; rr2 < p; ++rr2) {
        const int n  = (T_ - 1 - rr2) / p + 1;
        const int nt = (n + 63) >> 6;
        if (tix < nt) { r = rr2; n_r = n; q0 = (nt - 1 - tix) << 6; break; }
        tix -= nt;
        off += n;
    }
    if (r < 0) return;                            // block-uniform skip
    const int qn  = min(64, n_r - q0);
    const int kts = (q0 + qn + 63) >> 6;

    const int tid = threadIdx.x, lane = tid & 63, w = tid >> 6;
    const int ln = lane & 15, fq = lane >> 4;
    const int lsw = ln & 7;

    const size_t hs = (size_t)T_ * HD_;
    const _Float16* qb  = qkv + (size_t)(bh * 3) * hs;
    const _Float16* kb  = qb + hs;
    const _Float16* vtb = vt + (size_t)bh * HD_ * VTS + off;

    const int Lrow = lane >> 3;
    const int Lseg = (lane & 7) ^ Lrow;

    half8 aq0, aq1;
    {
        const int qi = min(q0 + w * 16 + ln, n_r - 1);
        const _Float16* qrow = qb + (size_t)(r + qi * p) * HD_;
        aq0 = *(const half8*)(qrow + fq * 8);
        aq1 = *(const half8*)(qrow + 32 + fq * 8);
        #pragma unroll
        for (int i2 = 0; i2 < 8; ++i2) {
            aq0[i2] = aq0[i2] * (_Float16)0.125f;   // exact exponent shift
            aq1[i2] = aq1[i2] * (_Float16)0.125f;
        }
    }

    f32x4 Od[4];
    float lp[4];
    #pragma unroll
    for (int nt = 0; nt < 4; ++nt)
        #pragma unroll
        for (int rr = 0; rr < 4; ++rr) Od[nt][rr] = 0.f;
    #pragma unroll
    for (int rr = 0; rr < 4; ++rr) lp[rr] = 0.f;

#define STAGE_KV(ktn, KT, VT) do {                                            \
        const int k0n = (ktn) << 6;                                           \
        _Pragma("unroll")                                                     \
        for (int i = 0; i < 2; ++i) {                                         \
            const int rowl = w * 16 + i * 8 + Lrow;                           \
            const int kj   = min(k0n + rowl, n_r - 1);                        \
            GLOAD_LDS16(kb + (size_t)(r + kj * p) * HD_ + Lseg * 8,           \
                        &KT[(w * 16 + i * 8) * 64]);                          \
            GLOAD_LDS16(vtb + (size_t)rowl * VTS + k0n + Lseg * 8,            \
                        &VT[(w * 16 + i * 8) * 64]);                          \
        }                                                                     \
    } while (0)

#define ATTN_ITER(kt, KT, VT, KTN, VTN) do {                                  \
        const int k0 = (kt) << 6;                                             \
        if ((kt) + 1 < kts) STAGE_KV((kt) + 1, KTN, VTN);                     \
        half8 bk0[4], bk1[4];                                                 \
        _Pragma("unroll")                                                     \
        for (int nt = 0; nt < 4; ++nt) {                                      \
            const int row = nt * 16 + ln;                                     \
            bk0[nt] = *(const half8*)&KT[row * 64 + ((fq ^ lsw) << 3)];       \
            bk1[nt] = *(const half8*)&KT[row * 64 + (((4 + fq) ^ lsw) << 3)]; \
        }                                                                     \
        f32x4 Sd[4];                                                          \
        __builtin_amdgcn_s_setprio(1);                                        \
        _Pragma("unroll")                                                     \
        for (int nt = 0; nt < 4; ++nt) {                                      \
            _Pragma("unroll")                                                 \
            for (int rr = 0; rr < 4; ++rr) Sd[nt][rr] = 0.f;                  \
            Sd[nt] = __builtin_amdgcn_mfma_f32_16x16x32_f16(aq0, bk0[nt], Sd[nt], 0, 0, 0); \
            Sd[nt] = __builtin_amdgcn_mfma_f32_16x16x32_f16(aq1, bk1[nt], Sd[nt], 0, 0, 0); \
        }                                                                     \
        __builtin_amdgcn_s_setprio(0);                                        \
        const bool diag = (k0 + 64 > q0);                                     \
        _Pragma("unroll")                                                     \
        for (int rr = 0; rr < 4; ++rr) {                                      \
            const int q_abs = q0 + w * 16 + fq * 4 + rr;                      \
            float s0 = Sd[0][rr], s1 = Sd[1][rr];                             \
            float s2 = Sd[2][rr], s3 = Sd[3][rr];                             \
            if (diag) {                                                       \
                if (k0 +  0 + ln > q_abs) s0 = -INFINITY;                     \
                if (k0 + 16 + ln > q_abs) s1 = -INFINITY;                     \
                if (k0 + 32 + ln > q_abs) s2 = -INFINITY;                     \
                if (k0 + 48 + ln > q_abs) s3 = -INFINITY;                     \
            }                                                                 \
            const float e0 = __expf(s0), e1 = __expf(s1);                     \
            const float e2 = __expf(s2), e3 = __expf(s3);                     \
            lp[rr] += (e0 + e1) + (e2 + e3);                                  \
            const int prow = fq * 4 + rr, rsw = prow & 7;                     \
            _Float16* pb = &Ps[w][prow * 64] + (ln & 7);                      \
            pb[(((ln >> 3) + 0) ^ rsw) << 3] = (_Float16)e0;                  \
            pb[(((ln >> 3) + 2) ^ rsw) << 3] = (_Float16)e1;                  \
            pb[(((ln >> 3) + 4) ^ rsw) << 3] = (_Float16)e2;                  \
            pb[(((ln >> 3) + 6) ^ rsw) << 3] = (_Float16)e3;                  \
        }                                                                     \
        half8 ap0 = *(const half8*)&Ps[w][ln * 64 + ((fq ^ lsw) << 3)];       \
        half8 ap1 = *(const half8*)&Ps[w][ln * 64 + (((4 + fq) ^ lsw) << 3)]; \
        __builtin_amdgcn_s_setprio(1);                                        \
        _Pragma("unroll")                                                     \
        for (int nt = 0; nt < 4; ++nt) {                                      \
            const int row = nt * 16 + ln;                                     \
            half8 bv0 = *(const half8*)&VT[row * 64 + ((fq ^ lsw) << 3)];     \
            half8 bv1 = *(const half8*)&VT[row * 64 + (((4 + fq) ^ lsw) << 3)]; \
            Od[nt] = __builtin_amdgcn_mfma_f32_16x16x32_f16(ap0, bv0, Od[nt], 0, 0, 0); \
            Od[nt] = __builtin_amdgcn_mfma_f32_16x16x32_f16(ap1, bv1, Od[nt], 0, 0, 0); \
        }                                                                     \
        __builtin_amdgcn_s_setprio(0);                                        \
        __syncthreads();                                                      \
    } while (0)

    STAGE_KV(0, Kt0, Vt0);
    __syncthreads();

    for (int kt = 0; kt < kts; kt += 2) {
        ATTN_ITER(kt, Kt0, Vt0, Kt1, Vt1);
        if (kt + 1 < kts)
            ATTN_ITER(kt + 1, Kt1, Vt1, Kt0, Vt0);
    }

    const int bb = bh >> 4, hh = bh & 15;
    #pragma unroll
    for (int rr = 0; rr < 4; ++rr) {
        float l = lp[rr];
        l += __shfl_xor(l, 1);
        l += __shfl_xor(l, 2);
        l += __shfl_xor(l, 4);
        l += __shfl_xor(l, 8);
        const int qq = w * 16 + fq * 4 + rr;
        if (q0 + qq < n_r) {
            const int t = r + (q0 + qq) * p;
            const float inv = 1.f / l;
            _Float16* orow = ao + ((size_t)bb * T_ + t) * D_ + hh * HD_;
            #pragma unroll
            for (int nt = 0; nt < 4; ++nt)
                orow[nt * 16 + ln] = (_Float16)(Od[nt][rr] * inv);
        }
    }
#undef STAGE_KV
#undef ATTN_ITER
}

// ---- the mega-kernel ----
__global__ __launch_bounds__(256, 2) void fused_all(
    const float* x, const int* periods, const float* w_qkv,
    const float* b_qkv, const float* w_out, const float* b_out, float* out,
    _Float16* x16, _Float16* wqkvT, _Float16* qkv16, _Float16* ao16,
    _Float16* woutT, _Float16* vt16)
{
    cg::grid_group gg = cg::this_grid();
    __shared__ __align__(16) unsigned char smem[40960];
    const int bid = blockIdx.x;
    const int GS  = gridDim.x;                    // multiple of 8
    const int M   = B_ * T_;                      // 4096

    // phase 0: cast x -> f16, transpose both weights
    for (int v = bid; v < 8192; v += GS)
        prep_unit(v, smem, x, x16, w_qkv, wqkvT, w_out, woutT);
    gg.sync();

    // phase 1: qkv = x @ w_qkv + b  (768 tile-units)
    for (int v = bid; v < 768; v += GS)
        qkv_unit(v, smem, x16, wqkvT, b_qkv, qkv16, M, 3 * D_, D_);
    gg.sync();

    // phase 2: gather+transpose V (1024 units)
    for (int v = bid; v < 1024; v += GS)
        vt_unit(v, smem, qkv16, periods, vt16);
    gg.sync();

    // phase 3: periodic sparse attention (1536 units)
    for (int v = bid; v < 1536; v += GS)
        attn_unit(v, smem, qkv16, vt16, periods, ao16);
    gg.sync();

    // phase 4: out = ao @ w_out + b  (512 tile-units)
    for (int v = bid; v < 512; v += GS)
        out_unit(v, smem, ao16, woutT, b_out, out, M, D_, D_);
}

// ---------------------------------------------------------------------------
extern "C" void kernel_launch(void* const* d_in, const int* in_sizes, int n_in,
                              void* d_out, int out_size, void* d_ws, size_t ws_size,
                              hipStream_t stream)
{
    const float* x       = (const float*)d_in[0];
    const int*   periods = (const int*)  d_in[1];
    const float* w_qkv   = (const float*)d_in[2];
    const float* b_qkv   = (const float*)d_in[3];
    const float* w_out   = (const float*)d_in[4];
    const float* b_out   = (const float*)d_in[5];
    float*       out     = (float*)d_out;
    (void)in_sizes; (void)n_in; (void)out_size; (void)ws_size;

    const int M = B_ * T_;                                  // 4096

    _Float16* x16   = (_Float16*)d_ws;                      // 8 MB
    _Float16* wqkvT = x16   + (size_t)M * D_;               // 6 MB  [3D][D]
    _Float16* qkv16 = wqkvT + (size_t)(3 * D_) * D_;        // 24 MB [b][h][3][T][64]
    _Float16* ao16  = qkv16 + (size_t)M * 3 * D_;           // 8 MB  [M][D]
    _Float16* woutT = ao16  + (size_t)M * D_;               // 2 MB  [D][D]
    _Float16* vt16  = woutT + (size_t)D_ * D_;              // 8.25 MB [bh][64][VTS]

    // co-resident grid: occupancy-derived, capped at 4/CU (LDS cap), mult of 8
    int maxb = 0;
    hipOccupancyMaxActiveBlocksPerMultiprocessor(&maxb, fused_all, 256, 0);
    if (maxb < 1) maxb = 1;
    int grid = maxb * 256;
    if (grid > 1024) grid = 1024;
    grid &= ~7;
    if (grid < 8) grid = 8;

    void* args[] = {
        (void*)&x, (void*)&periods, (void*)&w_qkv, (void*)&b_qkv,
        (void*)&w_out, (void*)&b_out, (void*)&out,
        (void*)&x16, (void*)&wqkvT, (void*)&qkv16, (void*)&ao16,
        (void*)&woutT, (void*)&vt16
    };
    hipLaunchCooperativeKernel(fused_all, dim3(grid), dim3(256), args, 0, stream);
}

// Round 8
// 170.975 us; speedup vs baseline: 2.1224x; 2.1224x over previous
//
#include <hip/hip_runtime.h>
#include <math.h>

#define B_  2
#define T_  2048
#define D_  1024
#define H_  16
#define HD_ 64
#define VTS (T_ + 64)   // padded vt row stride (halves)

typedef float    f32x4  __attribute__((ext_vector_type(4)));
typedef _Float16 half8  __attribute__((ext_vector_type(8)));
typedef _Float16 half4v __attribute__((ext_vector_type(4)));

#define GLOAD_LDS16(g, l)                                                     \
    __builtin_amdgcn_global_load_lds(                                         \
        (__attribute__((address_space(1))) void*)(g),                         \
        (__attribute__((address_space(3))) void*)(l), 16, 0, 0)

// ---------------------------------------------------------------------------
// fused prep: cast x -> f16 | transpose+cast w_qkv | transpose+cast w_out
// block ranges: [0,4096) cast, [4096,7168) w_qkv T, [7168,8192) w_out T
// ---------------------------------------------------------------------------
__device__ __forceinline__ void transpose_tile(
    const float* __restrict__ in, _Float16* __restrict__ out,
    int R, int C, int r0, int c0, int tid)
{
    __shared__ float tile[32][33];
    const int tx = tid & 31, ty = tid >> 5;
    #pragma unroll
    for (int q = 0; q < 4; ++q)
        tile[ty + 8 * q][tx] = in[(size_t)(r0 + ty + 8 * q) * C + c0 + tx];
    __syncthreads();
    #pragma unroll
    for (int q = 0; q < 4; ++q)
        out[(size_t)(c0 + ty + 8 * q) * R + r0 + tx] = (_Float16)tile[tx][ty + 8 * q];
}

__global__ __launch_bounds__(256) void prep_kernel(
    const float* __restrict__ x, _Float16* __restrict__ x16,
    const float* __restrict__ w_qkv, _Float16* __restrict__ wqkvT,
    const float* __restrict__ w_out, _Float16* __restrict__ woutT)
{
    const int bx = blockIdx.x, tid = threadIdx.x;
    if (bx < 4096) {
        const int i = (bx * 256 + tid) * 4;
        float4 v = *(const float4*)(x + i);
        half4v h;
        h[0] = (_Float16)v.x; h[1] = (_Float16)v.y;
        h[2] = (_Float16)v.z; h[3] = (_Float16)v.w;
        *(half4v*)(x16 + i) = h;
    } else if (bx < 7168) {
        const int bi = bx - 4096;                 // w_qkv: 1024 x 3072
        transpose_tile(w_qkv, wqkvT, D_, 3 * D_,
                       (bi / 96) * 32, (bi % 96) * 32, tid);
    } else {
        const int bi = bx - 7168;                 // w_out: 1024 x 1024
        transpose_tile(w_out, woutT, D_, D_,
                       (bi / 32) * 32, (bi % 32) * 32, tid);
    }
}

// ---------------------------------------------------------------------------
// f16 MFMA GEMM, BK=64, XOR-swizzled LDS staging (conflict-free frag reads).
// C = A[M][K] @ Bt[N][K]^T + bias. 128x128 tile, 4 waves, 4x4 MFMA/wave.
// LDS[row][q] = global[row][q ^ (row&7)]  (q = 16B seg, 8 per row)
// BX/BY are pre-swizzled tile indices (XCD-aware).  [R2-proven mapping]
// ---------------------------------------------------------------------------
#define GEMM_BODY(BX, BY)                                                     \
    __shared__ __align__(16) _Float16 As[128 * 64];                           \
    __shared__ __align__(16) _Float16 Bs[128 * 64];                           \
    const int tid  = threadIdx.x;                                             \
    const int lane = tid & 63;                                                \
    const int w    = tid >> 6;                                                \
    const int wm   = (w >> 1) * 64;                                           \
    const int wn   = (w & 1) * 64;                                            \
    const int srow = lane >> 3;               /* 0..7 */                      \
    const int sseg = (lane & 7) ^ srow;       /* swizzled fetch seg */        \
    const _Float16* gA = A  + (size_t)((BY) * 128 + w * 32 + srow) * K + sseg * 8; \
    const _Float16* gB = Bt + (size_t)((BX) * 128 + w * 32 + srow) * K + sseg * 8; \
    _Float16* lA = &As[(w * 32) * 64];                                        \
    _Float16* lB = &Bs[(w * 32) * 64];                                        \
    f32x4 acc[4][4];                                                          \
    _Pragma("unroll")                                                         \
    for (int i = 0; i < 4; ++i)                                               \
        _Pragma("unroll")                                                     \
        for (int j = 0; j < 4; ++j)                                           \
            _Pragma("unroll")                                                 \
            for (int rr = 0; rr < 4; ++rr) acc[i][j][rr] = 0.f;               \
    const int fr  = lane & 15;                                                \
    const int fq  = lane >> 4;                                                \
    const int fsw = fr & 7;                                                   \
    for (int k0 = 0; k0 < K; k0 += 64) {                                      \
        _Pragma("unroll")                                                     \
        for (int i = 0; i < 4; ++i) {                                         \
            GLOAD_LDS16(gA + (size_t)(i * 8) * K + k0, lA + i * 8 * 64);      \
            GLOAD_LDS16(gB + (size_t)(i * 8) * K + k0, lB + i * 8 * 64);      \
        }                                                                     \
        __syncthreads();                                                      \
        _Pragma("unroll")                                                     \
        for (int kk = 0; kk < 2; ++kk) {                                      \
            half8 af[4], bf[4];                                               \
            _Pragma("unroll")                                                 \
            for (int i = 0; i < 4; ++i)                                       \
                af[i] = *(const half8*)&As[(wm + i * 16 + fr) * 64 +          \
                                           ((kk * 4 + fq) ^ fsw) * 8];        \
            _Pragma("unroll")                                                 \
            for (int j = 0; j < 4; ++j)                                       \
                bf[j] = *(const half8*)&Bs[(wn + j * 16 + fr) * 64 +          \
                                           ((kk * 4 + fq) ^ fsw) * 8];        \
            _Pragma("unroll")                                                 \
            for (int i = 0; i < 4; ++i)                                       \
                _Pragma("unroll")                                             \
                for (int j = 0; j < 4; ++j)                                   \
                    acc[i][j] = __builtin_amdgcn_mfma_f32_16x16x32_f16(       \
                        af[i], bf[j], acc[i][j], 0, 0, 0);                    \
        }                                                                     \
        __syncthreads();                                                      \
    }

// qkv head-major output: dst[b][h][which][t][e], f16.
// 1D grid 768 blocks; XCD chunk: 96 consecutive tiles per XCD. [R2-proven]
__global__ __launch_bounds__(256, 4) void gemm_bt_f16_qkv(
    const _Float16* __restrict__ A, const _Float16* __restrict__ Bt,
    const float* __restrict__ bias, _Float16* __restrict__ C,
    int M, int N, int K)
{
    const int fid  = blockIdx.x;                  // 0..767
    const int wgid = (fid & 7) * 96 + (fid >> 3); // bijective (768 % 8 == 0)
    const int bx   = wgid % 24;                   // N tile
    const int by   = wgid / 24;                   // M tile
    GEMM_BODY(bx, by)
    #pragma unroll
    for (int j = 0; j < 4; ++j) {
        const int col = bx * 128 + wn + j * 16 + fr;
        const float bv = bias[col];
        const int which = col >> 10;
        const int hh    = (col >> 6) & 15;
        const int e     = col & 63;
        #pragma unroll
        for (int i = 0; i < 4; ++i) {
            const int row = by * 128 + wm + i * 16 + fq * 4;
            #pragma unroll
            for (int rr = 0; rr < 4; ++rr) {
                const int rowr = row + rr;
                const int b2 = rowr >> 11, t = rowr & 2047;
                const size_t dst =
                    (((size_t)(b2 * 16 + hh) * 3 + which) * 2048 + t) * 64 + e;
                C[dst] = (_Float16)(acc[i][j][rr] + bv);
            }
        }
    }
}

// ---------------------------------------------------------------------------
// out-projection GEMM, 128M x 64N tile -> 512 blocks (2/CU co-resident).
// R2-proven single-buffered structure (dbuf re-confirmed m99-null in R5;
// mega-kernel fusion refuted in R7: grid.sync + lost inter-launch overlap
// cost 3x, all pipes <5%).
// ---------------------------------------------------------------------------
__global__ __launch_bounds__(256, 4) void gemm_out_128x64(
    const _Float16* __restrict__ A, const _Float16* __restrict__ Bt,
    const float* __restrict__ bias, float* __restrict__ C,
    int M, int N, int K)
{
    __shared__ __align__(16) _Float16 As[128 * 64];
    __shared__ __align__(16) _Float16 Bs[64 * 64];
    const int fid  = blockIdx.x;                  // 0..511
    const int wgid = (fid & 7) * 64 + (fid >> 3); // bijective (512 % 8 == 0)
    const int bx   = wgid & 15;                   // N tile (64 wide)
    const int by   = wgid >> 4;                   // M tile (128 tall)
    const int tid  = threadIdx.x;
    const int lane = tid & 63;
    const int w    = tid >> 6;
    const int srow = lane >> 3;
    const int sseg = (lane & 7) ^ srow;
    const _Float16* gA = A  + (size_t)(by * 128 + w * 32 + srow) * K + sseg * 8;
    const _Float16* gB = Bt + (size_t)(bx * 64  + w * 16 + srow) * K + sseg * 8;
    _Float16* lA = &As[(w * 32) * 64];
    _Float16* lB = &Bs[(w * 16) * 64];
    f32x4 acc[2][4];
    #pragma unroll
    for (int i = 0; i < 2; ++i)
        #pragma unroll
        for (int j = 0; j < 4; ++j)
            #pragma unroll
            for (int rr = 0; rr < 4; ++rr) acc[i][j][rr] = 0.f;
    const int fr  = lane & 15;
    const int fq  = lane >> 4;
    const int fsw = fr & 7;
    for (int k0 = 0; k0 < K; k0 += 64) {
        #pragma unroll
        for (int i = 0; i < 4; ++i)
            GLOAD_LDS16(gA + (size_t)(i * 8) * K + k0, lA + i * 8 * 64);
        #pragma unroll
        for (int i = 0; i < 2; ++i)
            GLOAD_LDS16(gB + (size_t)(i * 8) * K + k0, lB + i * 8 * 64);
        __syncthreads();
        #pragma unroll
        for (int kk = 0; kk < 2; ++kk) {
            half8 af[2], bf[4];
            #pragma unroll
            for (int i = 0; i < 2; ++i)
                af[i] = *(const half8*)&As[(w * 32 + i * 16 + fr) * 64 +
                                           ((kk * 4 + fq) ^ fsw) * 8];
            #pragma unroll
            for (int j = 0; j < 4; ++j)
                bf[j] = *(const half8*)&Bs[(j * 16 + fr) * 64 +
                                           ((kk * 4 + fq) ^ fsw) * 8];
            #pragma unroll
            for (int i = 0; i < 2; ++i)
                #pragma unroll
                for (int j = 0; j < 4; ++j)
                    acc[i][j] = __builtin_amdgcn_mfma_f32_16x16x32_f16(
                        af[i], bf[j], acc[i][j], 0, 0, 0);
        }
        __syncthreads();
    }
    #pragma unroll
    for (int j = 0; j < 4; ++j) {
        const int col = bx * 64 + j * 16 + fr;
        const float bv = bias[col];
        #pragma unroll
        for (int i = 0; i < 2; ++i) {
            const int row = by * 128 + w * 32 + i * 16 + fq * 4;
            #pragma unroll
            for (int rr = 0; rr < 4; ++rr)
                C[(size_t)(row + rr) * N + col] = acc[i][j][rr] + bv;
        }
    }
}

// ---------------------------------------------------------------------------
// Gather+transpose V: vt[bh][d][c] (row stride VTS), column c enumerates each
// head's residue classes in order (r asc, j asc, t = r + j*p).
// 1D grid, bh == xcd (mod 8): vt write-allocates into the SAME XCD L2 the
// attention kernel will read it from.  [R2-proven mapping]
// ---------------------------------------------------------------------------
__global__ __launch_bounds__(256) void vt_gather_kernel(
    const _Float16* __restrict__ qkv, const int* __restrict__ periods,
    _Float16* __restrict__ vt)
{
    __shared__ _Float16 tile[64][72];
    const int fid = blockIdx.x;                   // 0..1023
    const int s   = fid >> 3;                     // 0..127
    const int bh  = (fid & 7) + 8 * (s >> 5);
    const int c0  = (s & 31) * 64;
    int p = periods[bh]; if (p < 1) p = 1;
    const int tid = threadIdx.x;
    const int rr = tid >> 2, seg = (tid & 3) * 16;

    const int c = c0 + rr;
    int r = 0, off = 0;
    for (; r < p - 1; ++r) {
        const int n = (T_ - 1 - r) / p + 1;
        if (c < off + n) break;
        off += n;
    }
    const int t = r + (c - off) * p;

    const size_t hs = (size_t)T_ * HD_;
    const _Float16* vrow = qkv + ((size_t)bh * 3 + 2) * hs + (size_t)t * HD_ + seg;
    *(half8*)&tile[rr][seg]     = *(const half8*)(vrow);
    *(half8*)&tile[rr][seg + 8] = *(const half8*)(vrow + 8);
    __syncthreads();

    _Float16* dst = vt + ((size_t)bh * HD_ + rr) * VTS + c0 + seg;
    half8 o0, o1;
    #pragma unroll
    for (int i = 0; i < 8; ++i) o0[i] = tile[seg + i][rr];
    #pragma unroll
    for (int i = 0; i < 8; ++i) o1[i] = tile[seg + 8 + i][rr];
    *(half8*)(dst)     = o0;
    *(half8*)(dst + 8) = o1;
}

// ---------------------------------------------------------------------------
// MFMA periodic-sparse attention (R9 structure): cooperative async staging +
// dbuf + no-max softmax, one barrier/iter, XOR-swizzled LDS.
// R2-proven mapping: bh == xcd (mod 8), 8-heads-per-group (s/48).
// Q pre-scaled by 1/8 at load (power-of-2, f16-exact; R5/R6-proven absmax-
// identical) — drops 16 v_mul_f32 per inner iteration.
// ---------------------------------------------------------------------------
__global__ __launch_bounds__(256, 4) void attn_mfma7_kernel(
    const _Float16* __restrict__ qkv, const _Float16* __restrict__ vt,
    const int* __restrict__ periods, _Float16* __restrict__ ao)
{
    __shared__ __align__(16) _Float16 Kt0[64 * 64], Kt1[64 * 64];
    __shared__ __align__(16) _Float16 Vt0[64 * 64], Vt1[64 * 64];
    __shared__ __align__(16) _Float16 Ps[4][16 * 64];

    const int fid = blockIdx.x;                   // 0..1535
    const int s   = fid >> 3;                     // 0..191
    const int bh  = (fid & 7) + 8 * (s / 48);     // bh == xcd (mod 8)
    int tix = s % 48;

    int p = periods[bh]; if (p < 1) p = 1;

    int r = -1, q0 = 0, n_r = 0, off = 0;
    for (int rr2 = 0; rr2 < p; ++rr2) {
        const int n  = (T_ - 1 - rr2) / p + 1;
        const int nt = (n + 63) >> 6;
        if (tix < nt) { r = rr2; n_r = n; q0 = (nt - 1 - tix) << 6; break; }
        tix -= nt;
        off += n;
    }
    if (r < 0) return;
    const int qn  = min(64, n_r - q0);
    const int kts = (q0 + qn + 63) >> 6;

    const int tid = threadIdx.x, lane = tid & 63, w = tid >> 6;
    const int ln = lane & 15, fq = lane >> 4;
    const int lsw = ln & 7;

    const size_t hs = (size_t)T_ * HD_;
    const _Float16* qb  = qkv + (size_t)(bh * 3) * hs;
    const _Float16* kb  = qb + hs;
    const _Float16* vtb = vt + (size_t)bh * HD_ * VTS + off;

    const int Lrow = lane >> 3;
    const int Lseg = (lane & 7) ^ Lrow;

    half8 aq0, aq1;
    {
        const int qi = min(q0 + w * 16 + ln, n_r - 1);
        const _Float16* qrow = qb + (size_t)(r + qi * p) * HD_;
        aq0 = *(const half8*)(qrow + fq * 8);
        aq1 = *(const half8*)(qrow + 32 + fq * 8);
        #pragma unroll
        for (int i2 = 0; i2 < 8; ++i2) {
            aq0[i2] = aq0[i2] * (_Float16)0.125f;   // exact exponent shift
            aq1[i2] = aq1[i2] * (_Float16)0.125f;
        }
    }

    f32x4 Od[4];
    float lp[4];
    #pragma unroll
    for (int nt = 0; nt < 4; ++nt)
        #pragma unroll
        for (int rr = 0; rr < 4; ++rr) Od[nt][rr] = 0.f;
    #pragma unroll
    for (int rr = 0; rr < 4; ++rr) lp[rr] = 0.f;

#define STAGE_KV(ktn, KT, VT) do {                                            \
        const int k0n = (ktn) << 6;                                           \
        _Pragma("unroll")                                                     \
        for (int i = 0; i < 2; ++i) {                                         \
            const int rowl = w * 16 + i * 8 + Lrow;                           \
            const int kj   = min(k0n + rowl, n_r - 1);                        \
            GLOAD_LDS16(kb + (size_t)(r + kj * p) * HD_ + Lseg * 8,           \
                        &KT[(w * 16 + i * 8) * 64]);                          \
            GLOAD_LDS16(vtb + (size_t)rowl * VTS + k0n + Lseg * 8,            \
                        &VT[(w * 16 + i * 8) * 64]);                          \
        }                                                                     \
    } while (0)

#define ATTN_ITER(kt, KT, VT, KTN, VTN) do {                                  \
        const int k0 = (kt) << 6;                                             \
        if ((kt) + 1 < kts) STAGE_KV((kt) + 1, KTN, VTN);                     \
        half8 bk0[4], bk1[4];                                                 \
        _Pragma("unroll")                                                     \
        for (int nt = 0; nt < 4; ++nt) {                                      \
            const int row = nt * 16 + ln;                                     \
            bk0[nt] = *(const half8*)&KT[row * 64 + ((fq ^ lsw) << 3)];       \
            bk1[nt] = *(const half8*)&KT[row * 64 + (((4 + fq) ^ lsw) << 3)]; \
        }                                                                     \
        f32x4 Sd[4];                                                          \
        __builtin_amdgcn_s_setprio(1);                                        \
        _Pragma("unroll")                                                     \
        for (int nt = 0; nt < 4; ++nt) {                                      \
            _Pragma("unroll")                                                 \
            for (int rr = 0; rr < 4; ++rr) Sd[nt][rr] = 0.f;                  \
            Sd[nt] = __builtin_amdgcn_mfma_f32_16x16x32_f16(aq0, bk0[nt], Sd[nt], 0, 0, 0); \
            Sd[nt] = __builtin_amdgcn_mfma_f32_16x16x32_f16(aq1, bk1[nt], Sd[nt], 0, 0, 0); \
        }                                                                     \
        __builtin_amdgcn_s_setprio(0);                                        \
        const bool diag = (k0 + 64 > q0);                                     \
        _Pragma("unroll")                                                     \
        for (int rr = 0; rr < 4; ++rr) {                                      \
            const int q_abs = q0 + w * 16 + fq * 4 + rr;                      \
            float s0 = Sd[0][rr], s1 = Sd[1][rr];                             \
            float s2 = Sd[2][rr], s3 = Sd[3][rr];                             \
            if (diag) {                                                       \
                if (k0 +  0 + ln > q_abs) s0 = -INFINITY;                     \
                if (k0 + 16 + ln > q_abs) s1 = -INFINITY;                     \
                if (k0 + 32 + ln > q_abs) s2 = -INFINITY;                     \
                if (k0 + 48 + ln > q_abs) s3 = -INFINITY;                     \
            }                                                                 \
            const float e0 = __expf(s0), e1 = __expf(s1);                     \
            const float e2 = __expf(s2), e3 = __expf(s3);                     \
            lp[rr] += (e0 + e1) + (e2 + e3);                                  \
            const int prow = fq * 4 + rr, rsw = prow & 7;                     \
            _Float16* pb = &Ps[w][prow * 64] + (ln & 7);                      \
            pb[(((ln >> 3) + 0) ^ rsw) << 3] = (_Float16)e0;                  \
            pb[(((ln >> 3) + 2) ^ rsw) << 3] = (_Float16)e1;                  \
            pb[(((ln >> 3) + 4) ^ rsw) << 3] = (_Float16)e2;                  \
            pb[(((ln >> 3) + 6) ^ rsw) << 3] = (_Float16)e3;                  \
        }                                                                     \
        half8 ap0 = *(const half8*)&Ps[w][ln * 64 + ((fq ^ lsw) << 3)];       \
        half8 ap1 = *(const half8*)&Ps[w][ln * 64 + (((4 + fq) ^ lsw) << 3)]; \
        __builtin_amdgcn_s_setprio(1);                                        \
        _Pragma("unroll")                                                     \
        for (int nt = 0; nt < 4; ++nt) {                                      \
            const int row = nt * 16 + ln;                                     \
            half8 bv0 = *(const half8*)&VT[row * 64 + ((fq ^ lsw) << 3)];     \
            half8 bv1 = *(const half8*)&VT[row * 64 + (((4 + fq) ^ lsw) << 3)]; \
            Od[nt] = __builtin_amdgcn_mfma_f32_16x16x32_f16(ap0, bv0, Od[nt], 0, 0, 0); \
            Od[nt] = __builtin_amdgcn_mfma_f32_16x16x32_f16(ap1, bv1, Od[nt], 0, 0, 0); \
        }                                                                     \
        __builtin_amdgcn_s_setprio(0);                                        \
        __syncthreads();                                                      \
    } while (0)

    STAGE_KV(0, Kt0, Vt0);
    __syncthreads();

    for (int kt = 0; kt < kts; kt += 2) {
        ATTN_ITER(kt, Kt0, Vt0, Kt1, Vt1);
        if (kt + 1 < kts)
            ATTN_ITER(kt + 1, Kt1, Vt1, Kt0, Vt0);
    }

    const int bb = bh >> 4, hh = bh & 15;
    #pragma unroll
    for (int rr = 0; rr < 4; ++rr) {
        float l = lp[rr];
        l += __shfl_xor(l, 1);
        l += __shfl_xor(l, 2);
        l += __shfl_xor(l, 4);
        l += __shfl_xor(l, 8);
        const int qq = w * 16 + fq * 4 + rr;
        if (q0 + qq < n_r) {
            const int t = r + (q0 + qq) * p;
            const float inv = 1.f / l;
            _Float16* orow = ao + ((size_t)bb * T_ + t) * D_ + hh * HD_;
            #pragma unroll
            for (int nt = 0; nt < 4; ++nt)
                orow[nt * 16 + ln] = (_Float16)(Od[nt][rr] * inv);
        }
    }
#undef STAGE_KV
#undef ATTN_ITER
}

// ---------------------------------------------------------------------------
extern "C" void kernel_launch(void* const* d_in, const int* in_sizes, int n_in,
                              void* d_out, int out_size, void* d_ws, size_t ws_size,
                              hipStream_t stream)
{
    const float* x       = (const float*)d_in[0];
    const int*   periods = (const int*)  d_in[1];
    const float* w_qkv   = (const float*)d_in[2];
    const float* b_qkv   = (const float*)d_in[3];
    const float* w_out   = (const float*)d_in[4];
    const float* b_out   = (const float*)d_in[5];
    float*       out     = (float*)d_out;

    const int M = B_ * T_;                                  // 4096

    _Float16* x16   = (_Float16*)d_ws;                      // 8 MB
    _Float16* wqkvT = x16   + (size_t)M * D_;               // 6 MB  [3D][D]
    _Float16* qkv16 = wqkvT + (size_t)(3 * D_) * D_;        // 24 MB [b][h][3][T][64]
    _Float16* ao16  = qkv16 + (size_t)M * 3 * D_;           // 8 MB  [M][D]
    _Float16* woutT = ao16  + (size_t)M * D_;               // 2 MB  [D][D]
    _Float16* vt16  = woutT + (size_t)D_ * D_;              // 8.25 MB [bh][64][VTS]

    // 0) fused prep: cast x, transpose both weight matrices
    prep_kernel<<<8192, 256, 0, stream>>>(x, x16, w_qkv, wqkvT, w_out, woutT);

    // 1) qkv = x @ w_qkv + b_qkv  (f16 MFMA BK=64, head-major f16 out)
    gemm_bt_f16_qkv<<<768, 256, 0, stream>>>(
        x16, wqkvT, b_qkv, qkv16, M, 3 * D_, D_);

    // 1b) gather+transpose V, head->XCD affinity matching the attention kernel
    vt_gather_kernel<<<1024, 256, 0, stream>>>(qkv16, periods, vt16);

    // 2) periodic sparse attention -> ao16 (XCD affinity, R2 grouping)
    attn_mfma7_kernel<<<1536, 256, 0, stream>>>(qkv16, vt16, periods, ao16);

    // 3) out = ao @ w_out + b_out  (128x64 tile, 512 blocks, single-buffered)
    gemm_out_128x64<<<512, 256, 0, stream>>>(
        ao16, woutT, b_out, out, M, D_, D_);
}

// Round 9
// 170.304 us; speedup vs baseline: 2.1307x; 1.0039x over previous
//
#include <hip/hip_runtime.h>
#include <math.h>

#define B_  2
#define T_  2048
#define D_  1024
#define H_  16
#define HD_ 64
#define VTS (T_ + 64)   // padded vt row stride (halves)

typedef float    f32x4  __attribute__((ext_vector_type(4)));
typedef _Float16 half8  __attribute__((ext_vector_type(8)));
typedef _Float16 half4v __attribute__((ext_vector_type(4)));

#define GLOAD_LDS16(g, l)                                                     \
    __builtin_amdgcn_global_load_lds(                                         \
        (__attribute__((address_space(1))) void*)(g),                         \
        (__attribute__((address_space(3))) void*)(l), 16, 0, 0)

// ---------------------------------------------------------------------------
// fused prep: cast x -> f16 | transpose+cast w_qkv | transpose+cast w_out
// R9: G11 restructure — 3072 blocks (was 8192): cast at 32B/thread,
// transposes in 64x64 tiles via float[64][65] LDS (stride-65 -> column reads
// hit 2 lanes/bank = free; 4x fewer units, 4x fewer barriers per byte).
// block ranges: [0,2048) cast, [2048,2816) w_qkv T, [2816,3072) w_out T
// ---------------------------------------------------------------------------
__device__ __forceinline__ void transpose_tile64(
    const float* __restrict__ in, _Float16* __restrict__ out,
    int R, int C, int r0, int c0, int tid)
{
    __shared__ float tile[64][65];                // 16.6 KB
    const int tx = tid & 63, ty = tid >> 6;       // ty 0..3
    #pragma unroll
    for (int q = 0; q < 16; ++q)
        tile[ty + 4 * q][tx] = in[(size_t)(r0 + ty + 4 * q) * C + c0 + tx];
    __syncthreads();
    #pragma unroll
    for (int q = 0; q < 16; ++q)
        out[(size_t)(c0 + ty + 4 * q) * R + r0 + tx] = (_Float16)tile[tx][ty + 4 * q];
}

__global__ __launch_bounds__(256) void prep_kernel(
    const float* __restrict__ x, _Float16* __restrict__ x16,
    const float* __restrict__ w_qkv, _Float16* __restrict__ wqkvT,
    const float* __restrict__ w_out, _Float16* __restrict__ woutT)
{
    const int bx = blockIdx.x, tid = threadIdx.x;
    if (bx < 2048) {
        const int i = (bx * 256 + tid) * 8;       // 2048*256*8 = 4.19M = B*T*D
        float4 v0 = *(const float4*)(x + i);
        float4 v1 = *(const float4*)(x + i + 4);
        half8 h;
        h[0] = (_Float16)v0.x; h[1] = (_Float16)v0.y;
        h[2] = (_Float16)v0.z; h[3] = (_Float16)v0.w;
        h[4] = (_Float16)v1.x; h[5] = (_Float16)v1.y;
        h[6] = (_Float16)v1.z; h[7] = (_Float16)v1.w;
        *(half8*)(x16 + i) = h;
    } else if (bx < 2816) {
        const int bi = bx - 2048;                 // w_qkv: 1024x3072 = 16x48 tiles
        transpose_tile64(w_qkv, wqkvT, D_, 3 * D_,
                         (bi / 48) * 64, (bi % 48) * 64, tid);
    } else {
        const int bi = bx - 2816;                 // w_out: 1024x1024 = 16x16 tiles
        transpose_tile64(w_out, woutT, D_, D_,
                         (bi / 16) * 64, (bi % 16) * 64, tid);
    }
}

// ---------------------------------------------------------------------------
// f16 MFMA GEMM, BK=64, XOR-swizzled LDS staging (conflict-free frag reads).
// C = A[M][K] @ Bt[N][K]^T + bias. 128x128 tile, 4 waves, 4x4 MFMA/wave.
// LDS[row][q] = global[row][q ^ (row&7)]  (q = 16B seg, 8 per row)
// BX/BY are pre-swizzled tile indices (XCD-aware).  [R2-proven mapping]
// ---------------------------------------------------------------------------
#define GEMM_BODY(BX, BY)                                                     \
    __shared__ __align__(16) _Float16 As[128 * 64];                           \
    __shared__ __align__(16) _Float16 Bs[128 * 64];                           \
    const int tid  = threadIdx.x;                                             \
    const int lane = tid & 63;                                                \
    const int w    = tid >> 6;                                                \
    const int wm   = (w >> 1) * 64;                                           \
    const int wn   = (w & 1) * 64;                                            \
    const int srow = lane >> 3;               /* 0..7 */                      \
    const int sseg = (lane & 7) ^ srow;       /* swizzled fetch seg */        \
    const _Float16* gA = A  + (size_t)((BY) * 128 + w * 32 + srow) * K + sseg * 8; \
    const _Float16* gB = Bt + (size_t)((BX) * 128 + w * 32 + srow) * K + sseg * 8; \
    _Float16* lA = &As[(w * 32) * 64];                                        \
    _Float16* lB = &Bs[(w * 32) * 64];                                        \
    f32x4 acc[4][4];                                                          \
    _Pragma("unroll")                                                         \
    for (int i = 0; i < 4; ++i)                                               \
        _Pragma("unroll")                                                     \
        for (int j = 0; j < 4; ++j)                                           \
            _Pragma("unroll")                                                 \
            for (int rr = 0; rr < 4; ++rr) acc[i][j][rr] = 0.f;               \
    const int fr  = lane & 15;                                                \
    const int fq  = lane >> 4;                                                \
    const int fsw = fr & 7;                                                   \
    for (int k0 = 0; k0 < K; k0 += 64) {                                      \
        _Pragma("unroll")                                                     \
        for (int i = 0; i < 4; ++i) {                                         \
            GLOAD_LDS16(gA + (size_t)(i * 8) * K + k0, lA + i * 8 * 64);      \
            GLOAD_LDS16(gB + (size_t)(i * 8) * K + k0, lB + i * 8 * 64);      \
        }                                                                     \
        __syncthreads();                                                      \
        _Pragma("unroll")                                                     \
        for (int kk = 0; kk < 2; ++kk) {                                      \
            half8 af[4], bf[4];                                               \
            _Pragma("unroll")                                                 \
            for (int i = 0; i < 4; ++i)                                       \
                af[i] = *(const half8*)&As[(wm + i * 16 + fr) * 64 +          \
                                           ((kk * 4 + fq) ^ fsw) * 8];        \
            _Pragma("unroll")                                                 \
            for (int j = 0; j < 4; ++j)                                       \
                bf[j] = *(const half8*)&Bs[(wn + j * 16 + fr) * 64 +          \
                                           ((kk * 4 + fq) ^ fsw) * 8];        \
            _Pragma("unroll")                                                 \
            for (int i = 0; i < 4; ++i)                                       \
                _Pragma("unroll")                                             \
                for (int j = 0; j < 4; ++j)                                   \
                    acc[i][j] = __builtin_amdgcn_mfma_f32_16x16x32_f16(       \
                        af[i], bf[j], acc[i][j], 0, 0, 0);                    \
        }                                                                     \
        __syncthreads();                                                      \
    }

// qkv head-major output: dst[b][h][which][t][e], f16.
// 1D grid 768 blocks; XCD chunk: 96 consecutive tiles per XCD. [R2-proven]
__global__ __launch_bounds__(256, 4) void gemm_bt_f16_qkv(
    const _Float16* __restrict__ A, const _Float16* __restrict__ Bt,
    const float* __restrict__ bias, _Float16* __restrict__ C,
    int M, int N, int K)
{
    const int fid  = blockIdx.x;                  // 0..767
    const int wgid = (fid & 7) * 96 + (fid >> 3); // bijective (768 % 8 == 0)
    const int bx   = wgid % 24;                   // N tile
    const int by   = wgid / 24;                   // M tile
    GEMM_BODY(bx, by)
    #pragma unroll
    for (int j = 0; j < 4; ++j) {
        const int col = bx * 128 + wn + j * 16 + fr;
        const float bv = bias[col];
        const int which = col >> 10;
        const int hh    = (col >> 6) & 15;
        const int e     = col & 63;
        #pragma unroll
        for (int i = 0; i < 4; ++i) {
            const int row = by * 128 + wm + i * 16 + fq * 4;
            #pragma unroll
            for (int rr = 0; rr < 4; ++rr) {
                const int rowr = row + rr;
                const int b2 = rowr >> 11, t = rowr & 2047;
                const size_t dst =
                    (((size_t)(b2 * 16 + hh) * 3 + which) * 2048 + t) * 64 + e;
                C[dst] = (_Float16)(acc[i][j][rr] + bv);
            }
        }
    }
}

// ---------------------------------------------------------------------------
// out-projection GEMM, 128M x 64N tile -> 512 blocks (2/CU co-resident).
// R2-proven single-buffered structure (dbuf re-confirmed m99-null in R5;
// mega-kernel fusion refuted in R7: grid.sync + lost inter-launch overlap
// cost 3x, all pipes <5%).
// ---------------------------------------------------------------------------
__global__ __launch_bounds__(256, 4) void gemm_out_128x64(
    const _Float16* __restrict__ A, const _Float16* __restrict__ Bt,
    const float* __restrict__ bias, float* __restrict__ C,
    int M, int N, int K)
{
    __shared__ __align__(16) _Float16 As[128 * 64];
    __shared__ __align__(16) _Float16 Bs[64 * 64];
    const int fid  = blockIdx.x;                  // 0..511
    const int wgid = (fid & 7) * 64 + (fid >> 3); // bijective (512 % 8 == 0)
    const int bx   = wgid & 15;                   // N tile (64 wide)
    const int by   = wgid >> 4;                   // M tile (128 tall)
    const int tid  = threadIdx.x;
    const int lane = tid & 63;
    const int w    = tid >> 6;
    const int srow = lane >> 3;
    const int sseg = (lane & 7) ^ srow;
    const _Float16* gA = A  + (size_t)(by * 128 + w * 32 + srow) * K + sseg * 8;
    const _Float16* gB = Bt + (size_t)(bx * 64  + w * 16 + srow) * K + sseg * 8;
    _Float16* lA = &As[(w * 32) * 64];
    _Float16* lB = &Bs[(w * 16) * 64];
    f32x4 acc[2][4];
    #pragma unroll
    for (int i = 0; i < 2; ++i)
        #pragma unroll
        for (int j = 0; j < 4; ++j)
            #pragma unroll
            for (int rr = 0; rr < 4; ++rr) acc[i][j][rr] = 0.f;
    const int fr  = lane & 15;
    const int fq  = lane >> 4;
    const int fsw = fr & 7;
    for (int k0 = 0; k0 < K; k0 += 64) {
        #pragma unroll
        for (int i = 0; i < 4; ++i)
            GLOAD_LDS16(gA + (size_t)(i * 8) * K + k0, lA + i * 8 * 64);
        #pragma unroll
        for (int i = 0; i < 2; ++i)
            GLOAD_LDS16(gB + (size_t)(i * 8) * K + k0, lB + i * 8 * 64);
        __syncthreads();
        #pragma unroll
        for (int kk = 0; kk < 2; ++kk) {
            half8 af[2], bf[4];
            #pragma unroll
            for (int i = 0; i < 2; ++i)
                af[i] = *(const half8*)&As[(w * 32 + i * 16 + fr) * 64 +
                                           ((kk * 4 + fq) ^ fsw) * 8];
            #pragma unroll
            for (int j = 0; j < 4; ++j)
                bf[j] = *(const half8*)&Bs[(j * 16 + fr) * 64 +
                                           ((kk * 4 + fq) ^ fsw) * 8];
            #pragma unroll
            for (int i = 0; i < 2; ++i)
                #pragma unroll
                for (int j = 0; j < 4; ++j)
                    acc[i][j] = __builtin_amdgcn_mfma_f32_16x16x32_f16(
                        af[i], bf[j], acc[i][j], 0, 0, 0);
        }
        __syncthreads();
    }
    #pragma unroll
    for (int j = 0; j < 4; ++j) {
        const int col = bx * 64 + j * 16 + fr;
        const float bv = bias[col];
        #pragma unroll
        for (int i = 0; i < 2; ++i) {
            const int row = by * 128 + w * 32 + i * 16 + fq * 4;
            #pragma unroll
            for (int rr = 0; rr < 4; ++rr)
                C[(size_t)(row + rr) * N + col] = acc[i][j][rr] + bv;
        }
    }
}

// ---------------------------------------------------------------------------
// Gather+transpose V: vt[bh][d][c] (row stride VTS), column c enumerates each
// head's residue classes in order (r asc, j asc, t = r + j*p).
// 1D grid, bh == xcd (mod 8): vt write-allocates into the SAME XCD L2 the
// attention kernel will read it from.  [R2-proven mapping]
// ---------------------------------------------------------------------------
__global__ __launch_bounds__(256) void vt_gather_kernel(
    const _Float16* __restrict__ qkv, const int* __restrict__ periods,
    _Float16* __restrict__ vt)
{
    __shared__ _Float16 tile[64][72];
    const int fid = blockIdx.x;                   // 0..1023
    const int s   = fid >> 3;                     // 0..127
    const int bh  = (fid & 7) + 8 * (s >> 5);
    const int c0  = (s & 31) * 64;
    int p = periods[bh]; if (p < 1) p = 1;
    const int tid = threadIdx.x;
    const int rr = tid >> 2, seg = (tid & 3) * 16;

    const int c = c0 + rr;
    int r = 0, off = 0;
    for (; r < p - 1; ++r) {
        const int n = (T_ - 1 - r) / p + 1;
        if (c < off + n) break;
        off += n;
    }
    const int t = r + (c - off) * p;

    const size_t hs = (size_t)T_ * HD_;
    const _Float16* vrow = qkv + ((size_t)bh * 3 + 2) * hs + (size_t)t * HD_ + seg;
    *(half8*)&tile[rr][seg]     = *(const half8*)(vrow);
    *(half8*)&tile[rr][seg + 8] = *(const half8*)(vrow + 8);
    __syncthreads();

    _Float16* dst = vt + ((size_t)bh * HD_ + rr) * VTS + c0 + seg;
    half8 o0, o1;
    #pragma unroll
    for (int i = 0; i < 8; ++i) o0[i] = tile[seg + i][rr];
    #pragma unroll
    for (int i = 0; i < 8; ++i) o1[i] = tile[seg + 8 + i][rr];
    *(half8*)(dst)     = o0;
    *(half8*)(dst + 8) = o1;
}

// ---------------------------------------------------------------------------
// MFMA periodic-sparse attention (R9 structure): cooperative async staging +
// dbuf + no-max softmax, one barrier/iter, XOR-swizzled LDS.
// R2-proven mapping: bh == xcd (mod 8), 8-heads-per-group (s/48).
// Q pre-scaled by 1/8 at load (power-of-2, f16-exact; R5/R6/R8-proven
// absmax-identical) — drops 16 v_mul_f32 per inner iteration.
// ---------------------------------------------------------------------------
__global__ __launch_bounds__(256, 4) void attn_mfma7_kernel(
    const _Float16* __restrict__ qkv, const _Float16* __restrict__ vt,
    const int* __restrict__ periods, _Float16* __restrict__ ao)
{
    __shared__ __align__(16) _Float16 Kt0[64 * 64], Kt1[64 * 64];
    __shared__ __align__(16) _Float16 Vt0[64 * 64], Vt1[64 * 64];
    __shared__ __align__(16) _Float16 Ps[4][16 * 64];

    const int fid = blockIdx.x;                   // 0..1535
    const int s   = fid >> 3;                     // 0..191
    const int bh  = (fid & 7) + 8 * (s / 48);     // bh == xcd (mod 8)
    int tix = s % 48;

    int p = periods[bh]; if (p < 1) p = 1;

    int r = -1, q0 = 0, n_r = 0, off = 0;
    for (int rr2 = 0; rr2 < p; ++rr2) {
        const int n  = (T_ - 1 - rr2) / p + 1;
        const int nt = (n + 63) >> 6;
        if (tix < nt) { r = rr2; n_r = n; q0 = (nt - 1 - tix) << 6; break; }
        tix -= nt;
        off += n;
    }
    if (r < 0) return;
    const int qn  = min(64, n_r - q0);
    const int kts = (q0 + qn + 63) >> 6;

    const int tid = threadIdx.x, lane = tid & 63, w = tid >> 6;
    const int ln = lane & 15, fq = lane >> 4;
    const int lsw = ln & 7;

    const size_t hs = (size_t)T_ * HD_;
    const _Float16* qb  = qkv + (size_t)(bh * 3) * hs;
    const _Float16* kb  = qb + hs;
    const _Float16* vtb = vt + (size_t)bh * HD_ * VTS + off;

    const int Lrow = lane >> 3;
    const int Lseg = (lane & 7) ^ Lrow;

    half8 aq0, aq1;
    {
        const int qi = min(q0 + w * 16 + ln, n_r - 1);
        const _Float16* qrow = qb + (size_t)(r + qi * p) * HD_;
        aq0 = *(const half8*)(qrow + fq * 8);
        aq1 = *(const half8*)(qrow + 32 + fq * 8);
        #pragma unroll
        for (int i2 = 0; i2 < 8; ++i2) {
            aq0[i2] = aq0[i2] * (_Float16)0.125f;   // exact exponent shift
            aq1[i2] = aq1[i2] * (_Float16)0.125f;
        }
    }

    f32x4 Od[4];
    float lp[4];
    #pragma unroll
    for (int nt = 0; nt < 4; ++nt)
        #pragma unroll
        for (int rr = 0; rr < 4; ++rr) Od[nt][rr] = 0.f;
    #pragma unroll
    for (int rr = 0; rr < 4; ++rr) lp[rr] = 0.f;

#define STAGE_KV(ktn, KT, VT) do {                                            \
        const int k0n = (ktn) << 6;                                           \
        _Pragma("unroll")                                                     \
        for (int i = 0; i < 2; ++i) {                                         \
            const int rowl = w * 16 + i * 8 + Lrow;                           \
            const int kj   = min(k0n + rowl, n_r - 1);                        \
            GLOAD_LDS16(kb + (size_t)(r + kj * p) * HD_ + Lseg * 8,           \
                        &KT[(w * 16 + i * 8) * 64]);                          \
            GLOAD_LDS16(vtb + (size_t)rowl * VTS + k0n + Lseg * 8,            \
                        &VT[(w * 16 + i * 8) * 64]);                          \
        }                                                                     \
    } while (0)

#define ATTN_ITER(kt, KT, VT, KTN, VTN) do {                                  \
        const int k0 = (kt) << 6;                                             \
        if ((kt) + 1 < kts) STAGE_KV((kt) + 1, KTN, VTN);                     \
        half8 bk0[4], bk1[4];                                                 \
        _Pragma("unroll")                                                     \
        for (int nt = 0; nt < 4; ++nt) {                                      \
            const int row = nt * 16 + ln;                                     \
            bk0[nt] = *(const half8*)&KT[row * 64 + ((fq ^ lsw) << 3)];       \
            bk1[nt] = *(const half8*)&KT[row * 64 + (((4 + fq) ^ lsw) << 3)]; \
        }                                                                     \
        f32x4 Sd[4];                                                          \
        __builtin_amdgcn_s_setprio(1);                                        \
        _Pragma("unroll")                                                     \
        for (int nt = 0; nt < 4; ++nt) {                                      \
            _Pragma("unroll")                                                 \
            for (int rr = 0; rr < 4; ++rr) Sd[nt][rr] = 0.f;                  \
            Sd[nt] = __builtin_amdgcn_mfma_f32_16x16x32_f16(aq0, bk0[nt], Sd[nt], 0, 0, 0); \
            Sd[nt] = __builtin_amdgcn_mfma_f32_16x16x32_f16(aq1, bk1[nt], Sd[nt], 0, 0, 0); \
        }                                                                     \
        __builtin_amdgcn_s_setprio(0);                                        \
        const bool diag = (k0 + 64 > q0);                                     \
        _Pragma("unroll")                                                     \
        for (int rr = 0; rr < 4; ++rr) {                                      \
            const int q_abs = q0 + w * 16 + fq * 4 + rr;                      \
            float s0 = Sd[0][rr], s1 = Sd[1][rr];                             \
            float s2 = Sd[2][rr], s3 = Sd[3][rr];                             \
            if (diag) {                                                       \
                if (k0 +  0 + ln > q_abs) s0 = -INFINITY;                     \
                if (k0 + 16 + ln > q_abs) s1 = -INFINITY;                     \
                if (k0 + 32 + ln > q_abs) s2 = -INFINITY;                     \
                if (k0 + 48 + ln > q_abs) s3 = -INFINITY;                     \
            }                                                                 \
            const float e0 = __expf(s0), e1 = __expf(s1);                     \
            const float e2 = __expf(s2), e3 = __expf(s3);                     \
            lp[rr] += (e0 + e1) + (e2 + e3);                                  \
            const int prow = fq * 4 + rr, rsw = prow & 7;                     \
            _Float16* pb = &Ps[w][prow * 64] + (ln & 7);                      \
            pb[(((ln >> 3) + 0) ^ rsw) << 3] = (_Float16)e0;                  \
            pb[(((ln >> 3) + 2) ^ rsw) << 3] = (_Float16)e1;                  \
            pb[(((ln >> 3) + 4) ^ rsw) << 3] = (_Float16)e2;                  \
            pb[(((ln >> 3) + 6) ^ rsw) << 3] = (_Float16)e3;                  \
        }                                                                     \
        half8 ap0 = *(const half8*)&Ps[w][ln * 64 + ((fq ^ lsw) << 3)];       \
        half8 ap1 = *(const half8*)&Ps[w][ln * 64 + (((4 + fq) ^ lsw) << 3)]; \
        __builtin_amdgcn_s_setprio(1);                                        \
        _Pragma("unroll")                                                     \
        for (int nt = 0; nt < 4; ++nt) {                                      \
            const int row = nt * 16 + ln;                                     \
            half8 bv0 = *(const half8*)&VT[row * 64 + ((fq ^ lsw) << 3)];     \
            half8 bv1 = *(const half8*)&VT[row * 64 + (((4 + fq) ^ lsw) << 3)]; \
            Od[nt] = __builtin_amdgcn_mfma_f32_16x16x32_f16(ap0, bv0, Od[nt], 0, 0, 0); \
            Od[nt] = __builtin_amdgcn_mfma_f32_16x16x32_f16(ap1, bv1, Od[nt], 0, 0, 0); \
        }                                                                     \
        __builtin_amdgcn_s_setprio(0);                                        \
        __syncthreads();                                                      \
    } while (0)

    STAGE_KV(0, Kt0, Vt0);
    __syncthreads();

    for (int kt = 0; kt < kts; kt += 2) {
        ATTN_ITER(kt, Kt0, Vt0, Kt1, Vt1);
        if (kt + 1 < kts)
            ATTN_ITER(kt + 1, Kt1, Vt1, Kt0, Vt0);
    }

    const int bb = bh >> 4, hh = bh & 15;
    #pragma unroll
    for (int rr = 0; rr < 4; ++rr) {
        float l = lp[rr];
        l += __shfl_xor(l, 1);
        l += __shfl_xor(l, 2);
        l += __shfl_xor(l, 4);
        l += __shfl_xor(l, 8);
        const int qq = w * 16 + fq * 4 + rr;
        if (q0 + qq < n_r) {
            const int t = r + (q0 + qq) * p;
            const float inv = 1.f / l;
            _Float16* orow = ao + ((size_t)bb * T_ + t) * D_ + hh * HD_;
            #pragma unroll
            for (int nt = 0; nt < 4; ++nt)
                orow[nt * 16 + ln] = (_Float16)(Od[nt][rr] * inv);
        }
    }
#undef STAGE_KV
#undef ATTN_ITER
}

// ---------------------------------------------------------------------------
extern "C" void kernel_launch(void* const* d_in, const int* in_sizes, int n_in,
                              void* d_out, int out_size, void* d_ws, size_t ws_size,
                              hipStream_t stream)
{
    const float* x       = (const float*)d_in[0];
    const int*   periods = (const int*)  d_in[1];
    const float* w_qkv   = (const float*)d_in[2];
    const float* b_qkv   = (const float*)d_in[3];
    const float* w_out   = (const float*)d_in[4];
    const float* b_out   = (const float*)d_in[5];
    float*       out     = (float*)d_out;

    const int M = B_ * T_;                                  // 4096

    _Float16* x16   = (_Float16*)d_ws;                      // 8 MB
    _Float16* wqkvT = x16   + (size_t)M * D_;               // 6 MB  [3D][D]
    _Float16* qkv16 = wqkvT + (size_t)(3 * D_) * D_;        // 24 MB [b][h][3][T][64]
    _Float16* ao16  = qkv16 + (size_t)M * 3 * D_;           // 8 MB  [M][D]
    _Float16* woutT = ao16  + (size_t)M * D_;               // 2 MB  [D][D]
    _Float16* vt16  = woutT + (size_t)D_ * D_;              // 8.25 MB [bh][64][VTS]

    // 0) fused prep: cast x, transpose both weight matrices (G11: 3072 blocks)
    prep_kernel<<<3072, 256, 0, stream>>>(x, x16, w_qkv, wqkvT, w_out, woutT);

    // 1) qkv = x @ w_qkv + b_qkv  (f16 MFMA BK=64, head-major f16 out)
    gemm_bt_f16_qkv<<<768, 256, 0, stream>>>(
        x16, wqkvT, b_qkv, qkv16, M, 3 * D_, D_);

    // 1b) gather+transpose V, head->XCD affinity matching the attention kernel
    vt_gather_kernel<<<1024, 256, 0, stream>>>(qkv16, periods, vt16);

    // 2) periodic sparse attention -> ao16 (XCD affinity, R2 grouping)
    attn_mfma7_kernel<<<1536, 256, 0, stream>>>(qkv16, vt16, periods, ao16);

    // 3) out = ao @ w_out + b_out  (128x64 tile, 512 blocks, single-buffered)
    gemm_out_128x64<<<512, 256, 0, stream>>>(
        ao16, woutT, b_out, out, M, D_, D_);
}

// Round 10
// 167.228 us; speedup vs baseline: 2.1699x; 1.0184x over previous
//
#include <hip/hip_runtime.h>
#include <math.h>

#define B_  2
#define T_  2048
#define D_  1024
#define H_  16
#define HD_ 64
#define VTS (T_ + 64)   // padded vt row stride (halves)

typedef float    f32x4  __attribute__((ext_vector_type(4)));
typedef _Float16 half8  __attribute__((ext_vector_type(8)));
typedef _Float16 half4v __attribute__((ext_vector_type(4)));

#define GLOAD_LDS16(g, l)                                                     \
    __builtin_amdgcn_global_load_lds(                                         \
        (__attribute__((address_space(1))) void*)(g),                         \
        (__attribute__((address_space(3))) void*)(l), 16, 0, 0)

// ---------------------------------------------------------------------------
// fused prep: cast x -> f16 | transpose+cast w_qkv | transpose+cast w_out
// 3072 blocks: cast at 32B/thread, transposes in 64x64 tiles via
// float[64][65] LDS (stride-65 -> column reads 2 lanes/bank = free).
// block ranges: [0,2048) cast, [2048,2816) w_qkv T, [2816,3072) w_out T
// ---------------------------------------------------------------------------
__device__ __forceinline__ void transpose_tile64(
    const float* __restrict__ in, _Float16* __restrict__ out,
    int R, int C, int r0, int c0, int tid)
{
    __shared__ float tile[64][65];                // 16.6 KB
    const int tx = tid & 63, ty = tid >> 6;       // ty 0..3
    #pragma unroll
    for (int q = 0; q < 16; ++q)
        tile[ty + 4 * q][tx] = in[(size_t)(r0 + ty + 4 * q) * C + c0 + tx];
    __syncthreads();
    #pragma unroll
    for (int q = 0; q < 16; ++q)
        out[(size_t)(c0 + ty + 4 * q) * R + r0 + tx] = (_Float16)tile[tx][ty + 4 * q];
}

__global__ __launch_bounds__(256) void prep_kernel(
    const float* __restrict__ x, _Float16* __restrict__ x16,
    const float* __restrict__ w_qkv, _Float16* __restrict__ wqkvT,
    const float* __restrict__ w_out, _Float16* __restrict__ woutT)
{
    const int bx = blockIdx.x, tid = threadIdx.x;
    if (bx < 2048) {
        const int i = (bx * 256 + tid) * 8;       // 2048*256*8 = 4.19M = B*T*D
        float4 v0 = *(const float4*)(x + i);
        float4 v1 = *(const float4*)(x + i + 4);
        half8 h;
        h[0] = (_Float16)v0.x; h[1] = (_Float16)v0.y;
        h[2] = (_Float16)v0.z; h[3] = (_Float16)v0.w;
        h[4] = (_Float16)v1.x; h[5] = (_Float16)v1.y;
        h[6] = (_Float16)v1.z; h[7] = (_Float16)v1.w;
        *(half8*)(x16 + i) = h;
    } else if (bx < 2816) {
        const int bi = bx - 2048;                 // w_qkv: 1024x3072 = 16x48 tiles
        transpose_tile64(w_qkv, wqkvT, D_, 3 * D_,
                         (bi / 48) * 64, (bi % 48) * 64, tid);
    } else {
        const int bi = bx - 2816;                 // w_out: 1024x1024 = 16x16 tiles
        transpose_tile64(w_out, woutT, D_, D_,
                         (bi / 16) * 64, (bi % 16) * 64, tid);
    }
}

// ---------------------------------------------------------------------------
// f16 MFMA GEMM, BK=64, XOR-swizzled LDS staging (conflict-free frag reads).
// C = A[M][K] @ Bt[N][K]^T + bias. 128x128 tile, 4 waves, 4x4 MFMA/wave.
// LDS[row][q] = global[row][q ^ (row&7)]  (q = 16B seg, 8 per row)
// BX/BY are pre-swizzled tile indices (XCD-aware).  [R2-proven mapping]
// ---------------------------------------------------------------------------
#define GEMM_BODY(BX, BY)                                                     \
    __shared__ __align__(16) _Float16 As[128 * 64];                           \
    __shared__ __align__(16) _Float16 Bs[128 * 64];                           \
    const int tid  = threadIdx.x;                                             \
    const int lane = tid & 63;                                                \
    const int w    = tid >> 6;                                                \
    const int wm   = (w >> 1) * 64;                                           \
    const int wn   = (w & 1) * 64;                                            \
    const int srow = lane >> 3;               /* 0..7 */                      \
    const int sseg = (lane & 7) ^ srow;       /* swizzled fetch seg */        \
    const _Float16* gA = A  + (size_t)((BY) * 128 + w * 32 + srow) * K + sseg * 8; \
    const _Float16* gB = Bt + (size_t)((BX) * 128 + w * 32 + srow) * K + sseg * 8; \
    _Float16* lA = &As[(w * 32) * 64];                                        \
    _Float16* lB = &Bs[(w * 32) * 64];                                        \
    f32x4 acc[4][4];                                                          \
    _Pragma("unroll")                                                         \
    for (int i = 0; i < 4; ++i)                                               \
        _Pragma("unroll")                                                     \
        for (int j = 0; j < 4; ++j)                                           \
            _Pragma("unroll")                                                 \
            for (int rr = 0; rr < 4; ++rr) acc[i][j][rr] = 0.f;               \
    const int fr  = lane & 15;                                                \
    const int fq  = lane >> 4;                                                \
    const int fsw = fr & 7;                                                   \
    for (int k0 = 0; k0 < K; k0 += 64) {                                      \
        _Pragma("unroll")                                                     \
        for (int i = 0; i < 4; ++i) {                                         \
            GLOAD_LDS16(gA + (size_t)(i * 8) * K + k0, lA + i * 8 * 64);      \
            GLOAD_LDS16(gB + (size_t)(i * 8) * K + k0, lB + i * 8 * 64);      \
        }                                                                     \
        __syncthreads();                                                      \
        _Pragma("unroll")                                                     \
        for (int kk = 0; kk < 2; ++kk) {                                      \
            half8 af[4], bf[4];                                               \
            _Pragma("unroll")                                                 \
            for (int i = 0; i < 4; ++i)                                       \
                af[i] = *(const half8*)&As[(wm + i * 16 + fr) * 64 +          \
                                           ((kk * 4 + fq) ^ fsw) * 8];        \
            _Pragma("unroll")                                                 \
            for (int j = 0; j < 4; ++j)                                       \
                bf[j] = *(const half8*)&Bs[(wn + j * 16 + fr) * 64 +          \
                                           ((kk * 4 + fq) ^ fsw) * 8];        \
            _Pragma("unroll")                                                 \
            for (int i = 0; i < 4; ++i)                                       \
                _Pragma("unroll")                                             \
                for (int j = 0; j < 4; ++j)                                   \
                    acc[i][j] = __builtin_amdgcn_mfma_f32_16x16x32_f16(       \
                        af[i], bf[j], acc[i][j], 0, 0, 0);                    \
        }                                                                     \
        __syncthreads();                                                      \
    }

// qkv head-major output: dst[b][h][which][t][e], f16.
// 1D grid 768 blocks; XCD chunk: 96 consecutive tiles per XCD. [R2-proven]
__global__ __launch_bounds__(256, 4) void gemm_bt_f16_qkv(
    const _Float16* __restrict__ A, const _Float16* __restrict__ Bt,
    const float* __restrict__ bias, _Float16* __restrict__ C,
    int M, int N, int K)
{
    const int fid  = blockIdx.x;                  // 0..767
    const int wgid = (fid & 7) * 96 + (fid >> 3); // bijective (768 % 8 == 0)
    const int bx   = wgid % 24;                   // N tile
    const int by   = wgid / 24;                   // M tile
    GEMM_BODY(bx, by)
    #pragma unroll
    for (int j = 0; j < 4; ++j) {
        const int col = bx * 128 + wn + j * 16 + fr;
        const float bv = bias[col];
        const int which = col >> 10;
        const int hh    = (col >> 6) & 15;
        const int e     = col & 63;
        #pragma unroll
        for (int i = 0; i < 4; ++i) {
            const int row = by * 128 + wm + i * 16 + fq * 4;
            #pragma unroll
            for (int rr = 0; rr < 4; ++rr) {
                const int rowr = row + rr;
                const int b2 = rowr >> 11, t = rowr & 2047;
                const size_t dst =
                    (((size_t)(b2 * 16 + hh) * 3 + which) * 2048 + t) * 64 + e;
                C[dst] = (_Float16)(acc[i][j][rr] + bv);
            }
        }
    }
}

// ---------------------------------------------------------------------------
// out-projection GEMM, 128M x 64N tile -> 512 blocks (2/CU co-resident).
// R2-proven single-buffered structure (dbuf m99-null re-confirmed R5;
// fusion refuted R7; split-K rejected on absmax numerics).
// ---------------------------------------------------------------------------
__global__ __launch_bounds__(256, 4) void gemm_out_128x64(
    const _Float16* __restrict__ A, const _Float16* __restrict__ Bt,
    const float* __restrict__ bias, float* __restrict__ C,
    int M, int N, int K)
{
    __shared__ __align__(16) _Float16 As[128 * 64];
    __shared__ __align__(16) _Float16 Bs[64 * 64];
    const int fid  = blockIdx.x;                  // 0..511
    const int wgid = (fid & 7) * 64 + (fid >> 3); // bijective (512 % 8 == 0)
    const int bx   = wgid & 15;                   // N tile (64 wide)
    const int by   = wgid >> 4;                   // M tile (128 tall)
    const int tid  = threadIdx.x;
    const int lane = tid & 63;
    const int w    = tid >> 6;
    const int srow = lane >> 3;
    const int sseg = (lane & 7) ^ srow;
    const _Float16* gA = A  + (size_t)(by * 128 + w * 32 + srow) * K + sseg * 8;
    const _Float16* gB = Bt + (size_t)(bx * 64  + w * 16 + srow) * K + sseg * 8;
    _Float16* lA = &As[(w * 32) * 64];
    _Float16* lB = &Bs[(w * 16) * 64];
    f32x4 acc[2][4];
    #pragma unroll
    for (int i = 0; i < 2; ++i)
        #pragma unroll
        for (int j = 0; j < 4; ++j)
            #pragma unroll
            for (int rr = 0; rr < 4; ++rr) acc[i][j][rr] = 0.f;
    const int fr  = lane & 15;
    const int fq  = lane >> 4;
    const int fsw = fr & 7;
    for (int k0 = 0; k0 < K; k0 += 64) {
        #pragma unroll
        for (int i = 0; i < 4; ++i)
            GLOAD_LDS16(gA + (size_t)(i * 8) * K + k0, lA + i * 8 * 64);
        #pragma unroll
        for (int i = 0; i < 2; ++i)
            GLOAD_LDS16(gB + (size_t)(i * 8) * K + k0, lB + i * 8 * 64);
        __syncthreads();
        #pragma unroll
        for (int kk = 0; kk < 2; ++kk) {
            half8 af[2], bf[4];
            #pragma unroll
            for (int i = 0; i < 2; ++i)
                af[i] = *(const half8*)&As[(w * 32 + i * 16 + fr) * 64 +
                                           ((kk * 4 + fq) ^ fsw) * 8];
            #pragma unroll
            for (int j = 0; j < 4; ++j)
                bf[j] = *(const half8*)&Bs[(j * 16 + fr) * 64 +
                                           ((kk * 4 + fq) ^ fsw) * 8];
            #pragma unroll
            for (int i = 0; i < 2; ++i)
                #pragma unroll
                for (int j = 0; j < 4; ++j)
                    acc[i][j] = __builtin_amdgcn_mfma_f32_16x16x32_f16(
                        af[i], bf[j], acc[i][j], 0, 0, 0);
        }
        __syncthreads();
    }
    #pragma unroll
    for (int j = 0; j < 4; ++j) {
        const int col = bx * 64 + j * 16 + fr;
        const float bv = bias[col];
        #pragma unroll
        for (int i = 0; i < 2; ++i) {
            const int row = by * 128 + w * 32 + i * 16 + fq * 4;
            #pragma unroll
            for (int rr = 0; rr < 4; ++rr)
                C[(size_t)(row + rr) * N + col] = acc[i][j][rr] + bv;
        }
    }
}

// ---------------------------------------------------------------------------
// Gather+transpose V: vt[bh][d][c] (row stride VTS), column c enumerates each
// head's residue classes in order (r asc, j asc, t = r + j*p).
// 1D grid, bh == xcd (mod 8): vt write-allocates into the SAME XCD L2 the
// attention kernel will read it from.  [R2-proven mapping]
// ---------------------------------------------------------------------------
__global__ __launch_bounds__(256) void vt_gather_kernel(
    const _Float16* __restrict__ qkv, const int* __restrict__ periods,
    _Float16* __restrict__ vt)
{
    __shared__ _Float16 tile[64][72];
    const int fid = blockIdx.x;                   // 0..1023
    const int s   = fid >> 3;                     // 0..127
    const int bh  = (fid & 7) + 8 * (s >> 5);
    const int c0  = (s & 31) * 64;
    int p = periods[bh]; if (p < 1) p = 1;
    const int tid = threadIdx.x;
    const int rr = tid >> 2, seg = (tid & 3) * 16;

    const int c = c0 + rr;
    int r = 0, off = 0;
    for (; r < p - 1; ++r) {
        const int n = (T_ - 1 - r) / p + 1;
        if (c < off + n) break;
        off += n;
    }
    const int t = r + (c - off) * p;

    const size_t hs = (size_t)T_ * HD_;
    const _Float16* vrow = qkv + ((size_t)bh * 3 + 2) * hs + (size_t)t * HD_ + seg;
    *(half8*)&tile[rr][seg]     = *(const half8*)(vrow);
    *(half8*)&tile[rr][seg + 8] = *(const half8*)(vrow + 8);
    __syncthreads();

    _Float16* dst = vt + ((size_t)bh * HD_ + rr) * VTS + c0 + seg;
    half8 o0, o1;
    #pragma unroll
    for (int i = 0; i < 8; ++i) o0[i] = tile[seg + i][rr];
    #pragma unroll
    for (int i = 0; i < 8; ++i) o1[i] = tile[seg + 8 + i][rr];
    *(half8*)(dst)     = o0;
    *(half8*)(dst + 8) = o1;
}

// ---------------------------------------------------------------------------
// MFMA periodic-sparse attention: cooperative async staging + dbuf + no-max
// softmax, one barrier/iter, XOR-swizzled LDS.
// R2-proven mapping: bh == xcd (mod 8), 8-heads-per-group (s/48) — one head
// per XCD at a time (<1MB working set in 4MB L2).
// Q pre-scaled by 1/8 at load (power-of-2, f16-exact; absmax-identical).
// ---------------------------------------------------------------------------
__global__ __launch_bounds__(256, 4) void attn_mfma7_kernel(
    const _Float16* __restrict__ qkv, const _Float16* __restrict__ vt,
    const int* __restrict__ periods, _Float16* __restrict__ ao)
{
    __shared__ __align__(16) _Float16 Kt0[64 * 64], Kt1[64 * 64];
    __shared__ __align__(16) _Float16 Vt0[64 * 64], Vt1[64 * 64];
    __shared__ __align__(16) _Float16 Ps[4][16 * 64];

    const int fid = blockIdx.x;                   // 0..1535
    const int s   = fid >> 3;                     // 0..191
    const int bh  = (fid & 7) + 8 * (s / 48);     // bh == xcd (mod 8)
    int tix = s % 48;

    int p = periods[bh]; if (p < 1) p = 1;

    int r = -1, q0 = 0, n_r = 0, off = 0;
    for (int rr2 = 0; rr2 < p; ++rr2) {
        const int n  = (T_ - 1 - rr2) / p + 1;
        const int nt = (n + 63) >> 6;
        if (tix < nt) { r = rr2; n_r = n; q0 = (nt - 1 - tix) << 6; break; }
        tix -= nt;
        off += n;
    }
    if (r < 0) return;
    const int qn  = min(64, n_r - q0);
    const int kts = (q0 + qn + 63) >> 6;

    const int tid = threadIdx.x, lane = tid & 63, w = tid >> 6;
    const int ln = lane & 15, fq = lane >> 4;
    const int lsw = ln & 7;

    const size_t hs = (size_t)T_ * HD_;
    const _Float16* qb  = qkv + (size_t)(bh * 3) * hs;
    const _Float16* kb  = qb + hs;
    const _Float16* vtb = vt + (size_t)bh * HD_ * VTS + off;

    const int Lrow = lane >> 3;
    const int Lseg = (lane & 7) ^ Lrow;

    half8 aq0, aq1;
    {
        const int qi = min(q0 + w * 16 + ln, n_r - 1);
        const _Float16* qrow = qb + (size_t)(r + qi * p) * HD_;
        aq0 = *(const half8*)(qrow + fq * 8);
        aq1 = *(const half8*)(qrow + 32 + fq * 8);
        #pragma unroll
        for (int i2 = 0; i2 < 8; ++i2) {
            aq0[i2] = aq0[i2] * (_Float16)0.125f;   // exact exponent shift
            aq1[i2] = aq1[i2] * (_Float16)0.125f;
        }
    }

    f32x4 Od[4];
    float lp[4];
    #pragma unroll
    for (int nt = 0; nt < 4; ++nt)
        #pragma unroll
        for (int rr = 0; rr < 4; ++rr) Od[nt][rr] = 0.f;
    #pragma unroll
    for (int rr = 0; rr < 4; ++rr) lp[rr] = 0.f;

#define STAGE_KV(ktn, KT, VT) do {                                            \
        const int k0n = (ktn) << 6;                                           \
        _Pragma("unroll")                                                     \
        for (int i = 0; i < 2; ++i) {                                         \
            const int rowl = w * 16 + i * 8 + Lrow;                           \
            const int kj   = min(k0n + rowl, n_r - 1);                        \
            GLOAD_LDS16(kb + (size_t)(r + kj * p) * HD_ + Lseg * 8,           \
                        &KT[(w * 16 + i * 8) * 64]);                          \
            GLOAD_LDS16(vtb + (size_t)rowl * VTS + k0n + Lseg * 8,            \
                        &VT[(w * 16 + i * 8) * 64]);                          \
        }                                                                     \
    } while (0)

#define ATTN_ITER(kt, KT, VT, KTN, VTN) do {                                  \
        const int k0 = (kt) << 6;                                             \
        if ((kt) + 1 < kts) STAGE_KV((kt) + 1, KTN, VTN);                     \
        half8 bk0[4], bk1[4];                                                 \
        _Pragma("unroll")                                                     \
        for (int nt = 0; nt < 4; ++nt) {                                      \
            const int row = nt * 16 + ln;                                     \
            bk0[nt] = *(const half8*)&KT[row * 64 + ((fq ^ lsw) << 3)];       \
            bk1[nt] = *(const half8*)&KT[row * 64 + (((4 + fq) ^ lsw) << 3)]; \
        }                                                                     \
        f32x4 Sd[4];                                                          \
        __builtin_amdgcn_s_setprio(1);                                        \
        _Pragma("unroll")                                                     \
        for (int nt = 0; nt < 4; ++nt) {                                      \
            _Pragma("unroll")                                                 \
            for (int rr = 0; rr < 4; ++rr) Sd[nt][rr] = 0.f;                  \
            Sd[nt] = __builtin_amdgcn_mfma_f32_16x16x32_f16(aq0, bk0[nt], Sd[nt], 0, 0, 0); \
            Sd[nt] = __builtin_amdgcn_mfma_f32_16x16x32_f16(aq1, bk1[nt], Sd[nt], 0, 0, 0); \
        }                                                                     \
        __builtin_amdgcn_s_setprio(0);                                        \
        const bool diag = (k0 + 64 > q0);                                     \
        _Pragma("unroll")                                                     \
        for (int rr = 0; rr < 4; ++rr) {                                      \
            const int q_abs = q0 + w * 16 + fq * 4 + rr;                      \
            float s0 = Sd[0][rr], s1 = Sd[1][rr];                             \
            float s2 = Sd[2][rr], s3 = Sd[3][rr];                             \
            if (diag) {                                                       \
                if (k0 +  0 + ln > q_abs) s0 = -INFINITY;                     \
                if (k0 + 16 + ln > q_abs) s1 = -INFINITY;                     \
                if (k0 + 32 + ln > q_abs) s2 = -INFINITY;                     \
                if (k0 + 48 + ln > q_abs) s3 = -INFINITY;                     \
            }                                                                 \
            const float e0 = __expf(s0), e1 = __expf(s1);                     \
            const float e2 = __expf(s2), e3 = __expf(s3);                     \
            lp[rr] += (e0 + e1) + (e2 + e3);                                  \
            const int prow = fq * 4 + rr, rsw = prow & 7;                     \
            _Float16* pb = &Ps[w][prow * 64] + (ln & 7);                      \
            pb[(((ln >> 3) + 0) ^ rsw) << 3] = (_Float16)e0;                  \
            pb[(((ln >> 3) + 2) ^ rsw) << 3] = (_Float16)e1;                  \
            pb[(((ln >> 3) + 4) ^ rsw) << 3] = (_Float16)e2;                  \
            pb[(((ln >> 3) + 6) ^ rsw) << 3] = (_Float16)e3;                  \
        }                                                                     \
        half8 ap0 = *(const half8*)&Ps[w][ln * 64 + ((fq ^ lsw) << 3)];       \
        half8 ap1 = *(const half8*)&Ps[w][ln * 64 + (((4 + fq) ^ lsw) << 3)]; \
        __builtin_amdgcn_s_setprio(1);                                        \
        _Pragma("unroll")                                                     \
        for (int nt = 0; nt < 4; ++nt) {                                      \
            const int row = nt * 16 + ln;                                     \
            half8 bv0 = *(const half8*)&VT[row * 64 + ((fq ^ lsw) << 3)];     \
            half8 bv1 = *(const half8*)&VT[row * 64 + (((4 + fq) ^ lsw) << 3)]; \
            Od[nt] = __builtin_amdgcn_mfma_f32_16x16x32_f16(ap0, bv0, Od[nt], 0, 0, 0); \
            Od[nt] = __builtin_amdgcn_mfma_f32_16x16x32_f16(ap1, bv1, Od[nt], 0, 0, 0); \
        }                                                                     \
        __builtin_amdgcn_s_setprio(0);                                        \
        __syncthreads();                                                      \
    } while (0)

    STAGE_KV(0, Kt0, Vt0);
    __syncthreads();

    for (int kt = 0; kt < kts; kt += 2) {
        ATTN_ITER(kt, Kt0, Vt0, Kt1, Vt1);
        if (kt + 1 < kts)
            ATTN_ITER(kt + 1, Kt1, Vt1, Kt0, Vt0);
    }

    const int bb = bh >> 4, hh = bh & 15;
    #pragma unroll
    for (int rr = 0; rr < 4; ++rr) {
        float l = lp[rr];
        l += __shfl_xor(l, 1);
        l += __shfl_xor(l, 2);
        l += __shfl_xor(l, 4);
        l += __shfl_xor(l, 8);
        const int qq = w * 16 + fq * 4 + rr;
        if (q0 + qq < n_r) {
            const int t = r + (q0 + qq) * p;
            const float inv = 1.f / l;
            _Float16* orow = ao + ((size_t)bb * T_ + t) * D_ + hh * HD_;
            #pragma unroll
            for (int nt = 0; nt < 4; ++nt)
                orow[nt * 16 + ln] = (_Float16)(Od[nt][rr] * inv);
        }
    }
#undef STAGE_KV
#undef ATTN_ITER
}

// ---------------------------------------------------------------------------
extern "C" void kernel_launch(void* const* d_in, const int* in_sizes, int n_in,
                              void* d_out, int out_size, void* d_ws, size_t ws_size,
                              hipStream_t stream)
{
    const float* x       = (const float*)d_in[0];
    const int*   periods = (const int*)  d_in[1];
    const float* w_qkv   = (const float*)d_in[2];
    const float* b_qkv   = (const float*)d_in[3];
    const float* w_out   = (const float*)d_in[4];
    const float* b_out   = (const float*)d_in[5];
    float*       out     = (float*)d_out;

    const int M = B_ * T_;                                  // 4096

    _Float16* x16   = (_Float16*)d_ws;                      // 8 MB
    _Float16* wqkvT = x16   + (size_t)M * D_;               // 6 MB  [3D][D]
    _Float16* qkv16 = wqkvT + (size_t)(3 * D_) * D_;        // 24 MB [b][h][3][T][64]
    _Float16* ao16  = qkv16 + (size_t)M * 3 * D_;           // 8 MB  [M][D]
    _Float16* woutT = ao16  + (size_t)M * D_;               // 2 MB  [D][D]
    _Float16* vt16  = woutT + (size_t)D_ * D_;              // 8.25 MB [bh][64][VTS]

    // 0) fused prep: cast x, transpose both weight matrices
    prep_kernel<<<3072, 256, 0, stream>>>(x, x16, w_qkv, wqkvT, w_out, woutT);

    // 1) qkv = x @ w_qkv + b_qkv  (f16 MFMA BK=64, head-major f16 out)
    gemm_bt_f16_qkv<<<768, 256, 0, stream>>>(
        x16, wqkvT, b_qkv, qkv16, M, 3 * D_, D_);

    // 1b) gather+transpose V, head->XCD affinity matching the attention kernel
    vt_gather_kernel<<<1024, 256, 0, stream>>>(qkv16, periods, vt16);

    // 2) periodic sparse attention -> ao16 (XCD affinity, R2 grouping)
    attn_mfma7_kernel<<<1536, 256, 0, stream>>>(qkv16, vt16, periods, ao16);

    // 3) out = ao @ w_out + b_out  (128x64 tile, 512 blocks, single-buffered)
    gemm_out_128x64<<<512, 256, 0, stream>>>(
        ao16, woutT, b_out, out, M, D_, D_);
}